// Round 5
// baseline (332.315 us; speedup 1.0000x reference)
//
#include <hip/hip_runtime.h>
#include <hip/hip_runtime_api.h>

#define N_NODES 50000
#define N_EDGES 800000
#define N_PAIRS 8192
#define N_SLOTS (2 * N_PAIRS)
#define CAP     64          // per-node bucket capacity; P(deg>63)~5e-19

// Sinkhorn constants (log2 domain):
//   C2 = -(C/eps + ln32)*log2e ; potentials kept in /(eps*ln2) units
#define INV_EPS   20.0f
#define LOG2E_F   1.4426950408889634f
#define LN2_F     0.6931471805599453f
#define LN32_F    3.4657359027997265f
#define EPS_F     0.05f

#define SINK_BLOCKS 4096

typedef float f2 __attribute__((ext_vector_type(2)));

// ---------------------------------------- scatter into fixed-cap buckets
// Unconditional: buckets for non-pair nodes are written but never read.
__global__ __launch_bounds__(256) void k_scatter(
        const int* __restrict__ eidx,
        int* __restrict__ cnt, int* __restrict__ bucket) {
    int t = blockIdx.x * 256 + threadIdx.x;   // exact grid: 800000/256
    int dst = eidx[N_EDGES + t];
    int pos = atomicAdd(&cnt[dst], 1);
    if (pos < CAP) bucket[dst * CAP + pos] = eidx[t];
}

// ------------------------------------ fused gather + GEMM + relu
__global__ __launch_bounds__(256) void k_gemm(
        const int* __restrict__ pairs, const float* __restrict__ x,
        const int* __restrict__ cnt, const int* __restrict__ bucket,
        const float* __restrict__ W, float* __restrict__ Z) {
    __shared__ __align__(16) float Us[16 * 128];
    int sbase = blockIdx.x * 16;
    int t = threadIdx.x;
    int wave = t >> 6, lane = t & 63;

    #pragma unroll
    for (int rr = 0; rr < 4; ++rr) {
        int r = wave * 4 + rr;
        int node = pairs[sbase + r];
        int n = cnt[node];
        int m = (n < CAP) ? n : CAP;
        const int* bk = bucket + node * CAP;
        float ax = 0.0f, ay = 0.0f;
        int k = 0;
        for (; k + 4 <= m; k += 4) {
            int s0 = bk[k], s1 = bk[k + 1], s2 = bk[k + 2], s3 = bk[k + 3];
            float2 v0 = *(const float2*)(x + (size_t)s0 * 128 + lane * 2);
            float2 v1 = *(const float2*)(x + (size_t)s1 * 128 + lane * 2);
            float2 v2 = *(const float2*)(x + (size_t)s2 * 128 + lane * 2);
            float2 v3 = *(const float2*)(x + (size_t)s3 * 128 + lane * 2);
            ax += (v0.x + v1.x) + (v2.x + v3.x);
            ay += (v0.y + v1.y) + (v2.y + v3.y);
        }
        for (; k < m; ++k) {
            int s0 = bk[k];
            float2 v0 = *(const float2*)(x + (size_t)s0 * 128 + lane * 2);
            ax += v0.x;
            ay += v0.y;
        }
        float rdeg = 1.0f / fmaxf((float)n, 1.0f);
        float2 xv = *(const float2*)(x + (size_t)node * 128 + lane * 2);
        float2 o;
        o.x = fmaf(ax, rdeg, xv.x);
        o.y = fmaf(ay, rdeg, xv.y);
        *(float2*)(Us + r * 128 + lane * 2) = o;
    }
    __syncthreads();

    int jq = t & 63;   // column quad: cols 4*jq..4*jq+3
    int rq = t >> 6;   // row quad group: rows 4*rq..4*rq+3
    float acc[4][4] = {};
    const float4* Wv = (const float4*)W;   // W[128][256]

    for (int k4 = 0; k4 < 32; ++k4) {
        float4 wv[4];
        #pragma unroll
        for (int i = 0; i < 4; ++i) wv[i] = Wv[(size_t)(k4 * 4 + i) * 64 + jq];
        #pragma unroll
        for (int r = 0; r < 4; ++r) {
            float4 uv = *(const float4*)(Us + (rq * 4 + r) * 128 + k4 * 4);
            float uk0 = uv.x, uk1 = uv.y, uk2 = uv.z, uk3 = uv.w;
            acc[r][0] = fmaf(uk0, wv[0].x, acc[r][0]);
            acc[r][1] = fmaf(uk0, wv[0].y, acc[r][1]);
            acc[r][2] = fmaf(uk0, wv[0].z, acc[r][2]);
            acc[r][3] = fmaf(uk0, wv[0].w, acc[r][3]);
            acc[r][0] = fmaf(uk1, wv[1].x, acc[r][0]);
            acc[r][1] = fmaf(uk1, wv[1].y, acc[r][1]);
            acc[r][2] = fmaf(uk1, wv[1].z, acc[r][2]);
            acc[r][3] = fmaf(uk1, wv[1].w, acc[r][3]);
            acc[r][0] = fmaf(uk2, wv[2].x, acc[r][0]);
            acc[r][1] = fmaf(uk2, wv[2].y, acc[r][1]);
            acc[r][2] = fmaf(uk2, wv[2].z, acc[r][2]);
            acc[r][3] = fmaf(uk2, wv[2].w, acc[r][3]);
            acc[r][0] = fmaf(uk3, wv[3].x, acc[r][0]);
            acc[r][1] = fmaf(uk3, wv[3].y, acc[r][1]);
            acc[r][2] = fmaf(uk3, wv[3].z, acc[r][2]);
            acc[r][3] = fmaf(uk3, wv[3].w, acc[r][3]);
        }
    }

    #pragma unroll
    for (int r = 0; r < 4; ++r) {
        float4 o;
        o.x = fmaxf(acc[r][0], 0.0f);
        o.y = fmaxf(acc[r][1], 0.0f);
        o.z = fmaxf(acc[r][2], 0.0f);
        o.w = fmaxf(acc[r][3], 0.0f);
        *(float4*)(Z + (size_t)(sbase + rq * 4 + r) * 256 + jq * 4) = o;
    }
}

// ------------------------------------------------------------------- sinkhorn
// 128-thread blocks (2 waves).
//  blocks [0,2048):    diagonal — one wave per TWO pairs (dual-chain ILP).
//  blocks [2048,4096): off-diagonal — HALF-WAVE per pair (2 pairs/wave).
// Last finished block computes the final distortion reduction (fused
// finalize): threadfence + agent-scope counter; dist read via agent-scope
// atomic loads (L1 bypass — per-XCD L2s are not coherent).
__global__ __launch_bounds__(128) void k_sinkhorn(
        const float* __restrict__ Z, float* __restrict__ dist,
        int* __restrict__ done, const float* __restrict__ gd,
        float* __restrict__ out) {
    __shared__ __align__(16) float smem[2][1280];   // 10240 B
    __shared__ int is_last;

    int w = threadIdx.x >> 6;
    int lane = threadIdx.x & 63;
    float* S = &smem[w][0];
    const float CSCALE = -INV_EPS * LOG2E_F;
    const float CBIAS  = -LN32_F * LOG2E_F;

    if (blockIdx.x < 2048) {
        // ==== diagonal path: 2 pairs/wave, dual independent chains ====
        int h = lane >> 5, i = lane & 31;
        int q = (i >> 4) & 1;                 // k-half this lane reads
        int ip = i ^ 16;                      // partner row
        int P0 = blockIdx.x * 4 + w * 2;      // 2048*2*2 = 8192 pairs

        float* sP   = S;                      // 512 floats, transient per build
        float* swv0 = S + 512;
        float* spv0 = S + 576;
        float* swv1 = S + 640;
        float* spv1 = S + 704;

        f2 KA0[8], KB0[8], KA1[8], KB1[8];

        auto build = [&](f2 (&KA)[8], f2 (&KB)[8], int P) {
            int src = h ? (N_PAIRS + P) : P;
            float* sPh = sP + h * 256;
            {
                const float4* zp = (const float4*)(Z + (size_t)src * 256);
                *(float4*)(&sPh[i * 8])     = zp[i * 2];
                *(float4*)(&sPh[i * 8 + 4]) = zp[i * 2 + 1];
            }
            const f2* xp = (const f2*)(&sPh[i * 8]);
            f2 x0 = xp[0], x1 = xp[1], x2 = xp[2], x3 = xp[3];
            const f2* bp = (const f2*)(&sPh[ip * 8]);
            f2 b0 = bp[0], b1 = bp[1], b2 = bp[2], b3 = bp[3];
            #pragma unroll
            for (int t = 0; t < 16; ++t) {
                int j = q * 16 + t;
                const f2* yp = (const f2*)(&sPh[j * 8]);
                f2 y0 = yp[0], y1 = yp[1], y2 = yp[2], y3 = yp[3];
                f2 d, s2;
                d = x0 - y0; s2 = d * d;
                d = x1 - y1; s2 = __builtin_elementwise_fma(d, d, s2);
                d = x2 - y2; s2 = __builtin_elementwise_fma(d, d, s2);
                d = x3 - y3; s2 = __builtin_elementwise_fma(d, d, s2);
                float d2 = s2.x + s2.y + 1e-12f;
                KA[t >> 1][t & 1] = __builtin_amdgcn_exp2f(
                    fmaf(__builtin_amdgcn_sqrtf(d2), CSCALE, CBIAS));
                d = b0 - y0; s2 = d * d;
                d = b1 - y1; s2 = __builtin_elementwise_fma(d, d, s2);
                d = b2 - y2; s2 = __builtin_elementwise_fma(d, d, s2);
                d = b3 - y3; s2 = __builtin_elementwise_fma(d, d, s2);
                float e2 = s2.x + s2.y + 1e-12f;
                KB[t >> 1][t & 1] = __builtin_amdgcn_exp2f(
                    fmaf(__builtin_amdgcn_sqrtf(e2), CSCALE, CBIAS));
            }
        };
        build(KA0, KB0, P0);
        build(KA1, KB1, P0 + 1);

        float pp0 = 0.0f, pp1 = 0.0f, E0 = 1.0f, E1 = 1.0f;
        float w0c = 1.0f, w0p = 1.0f, w1c = 1.0f, w1p = 1.0f;
        swv0[lane] = 1.0f;
        swv1[lane] = 1.0f;

        const int blens[9] = {4, 12, 12, 12, 12, 12, 12, 12, 12};  // 100 T-steps
        #pragma unroll 1
        for (int blk = 0; blk < 9; ++blk) {
            int L = blens[blk];
            #pragma unroll 1
            for (int s = 0; s < L; ++s) {
                const float4* wp0 = (const float4*)(&swv0[h * 32 + q * 16]);
                const float4* wp1 = (const float4*)(&swv1[h * 32 + q * 16]);
                float4 A0 = wp0[0], A1 = wp0[1], A2 = wp0[2], A3 = wp0[3];
                float4 B0 = wp1[0], B1 = wp1[1], B2 = wp1[2], B3 = wp1[3];
                // ---- chain 0 dot ----
                f2 aA0 = KA0[0] * f2{A0.x, A0.y};
                f2 aA1 = KA0[1] * f2{A0.z, A0.w};
                f2 aB0 = KB0[0] * f2{A0.x, A0.y};
                f2 aB1 = KB0[1] * f2{A0.z, A0.w};
                aA0 = __builtin_elementwise_fma(KA0[2], f2{A1.x, A1.y}, aA0);
                aA1 = __builtin_elementwise_fma(KA0[3], f2{A1.z, A1.w}, aA1);
                aB0 = __builtin_elementwise_fma(KB0[2], f2{A1.x, A1.y}, aB0);
                aB1 = __builtin_elementwise_fma(KB0[3], f2{A1.z, A1.w}, aB1);
                aA0 = __builtin_elementwise_fma(KA0[4], f2{A2.x, A2.y}, aA0);
                aA1 = __builtin_elementwise_fma(KA0[5], f2{A2.z, A2.w}, aA1);
                aB0 = __builtin_elementwise_fma(KB0[4], f2{A2.x, A2.y}, aB0);
                aB1 = __builtin_elementwise_fma(KB0[5], f2{A2.z, A2.w}, aB1);
                aA0 = __builtin_elementwise_fma(KA0[6], f2{A3.x, A3.y}, aA0);
                aA1 = __builtin_elementwise_fma(KA0[7], f2{A3.z, A3.w}, aA1);
                aB0 = __builtin_elementwise_fma(KB0[6], f2{A3.x, A3.y}, aB0);
                aB1 = __builtin_elementwise_fma(KB0[7], f2{A3.z, A3.w}, aB1);
                f2 aa0 = aA0 + aA1;
                f2 bb0 = aB0 + aB1;
                float pa0 = aa0.x + aa0.y;
                float pb0 = bb0.x + bb0.y;
                // ---- chain 1 dot ----
                f2 cA0 = KA1[0] * f2{B0.x, B0.y};
                f2 cA1 = KA1[1] * f2{B0.z, B0.w};
                f2 cB0 = KB1[0] * f2{B0.x, B0.y};
                f2 cB1 = KB1[1] * f2{B0.z, B0.w};
                cA0 = __builtin_elementwise_fma(KA1[2], f2{B1.x, B1.y}, cA0);
                cA1 = __builtin_elementwise_fma(KA1[3], f2{B1.z, B1.w}, cA1);
                cB0 = __builtin_elementwise_fma(KB1[2], f2{B1.x, B1.y}, cB0);
                cB1 = __builtin_elementwise_fma(KB1[3], f2{B1.z, B1.w}, cB1);
                cA0 = __builtin_elementwise_fma(KA1[4], f2{B2.x, B2.y}, cA0);
                cA1 = __builtin_elementwise_fma(KA1[5], f2{B2.z, B2.w}, cA1);
                cB0 = __builtin_elementwise_fma(KB1[4], f2{B2.x, B2.y}, cB0);
                cB1 = __builtin_elementwise_fma(KB1[5], f2{B2.z, B2.w}, cB1);
                cA0 = __builtin_elementwise_fma(KA1[6], f2{B3.x, B3.y}, cA0);
                cA1 = __builtin_elementwise_fma(KA1[7], f2{B3.z, B3.w}, cA1);
                cB0 = __builtin_elementwise_fma(KB1[6], f2{B3.x, B3.y}, cB0);
                cB1 = __builtin_elementwise_fma(KB1[7], f2{B3.z, B3.w}, cB1);
                f2 aa1 = cA0 + cA1;
                f2 bb1 = cB0 + cB1;
                float pa1 = aa1.x + aa1.y;
                float pb1 = bb1.x + bb1.y;
                // combine + update, both chains
                float o0 = __shfl_xor(pb0, 16);
                float o1 = __shfl_xor(pb1, 16);
                w0p = w0c;
                w0c = __builtin_amdgcn_rcpf(pa0 + o0) * E0;
                w1p = w1c;
                w1c = __builtin_amdgcn_rcpf(pa1 + o1) * E1;
                swv0[h * 32 + i] = w0c;
                swv1[h * 32 + i] = w1c;
            }
            if (blk < 8) {
                float d0 = __builtin_amdgcn_logf(w0c);
                float d1 = __builtin_amdgcn_logf(w1c);
                pp0 += d0;
                pp1 += d1;
                spv0[h * 32 + i] = d0;
                spv1[h * 32 + i] = d1;
                {
                    const float4* dv = (const float4*)(&spv0[h * 32 + q * 16]);
                    float4 D0 = dv[0], D1 = dv[1], D2 = dv[2], D3 = dv[3];
                    float ex[16];
                    ex[0]  = __builtin_amdgcn_exp2f(D0.x);
                    ex[1]  = __builtin_amdgcn_exp2f(D0.y);
                    ex[2]  = __builtin_amdgcn_exp2f(D0.z);
                    ex[3]  = __builtin_amdgcn_exp2f(D0.w);
                    ex[4]  = __builtin_amdgcn_exp2f(D1.x);
                    ex[5]  = __builtin_amdgcn_exp2f(D1.y);
                    ex[6]  = __builtin_amdgcn_exp2f(D1.z);
                    ex[7]  = __builtin_amdgcn_exp2f(D1.w);
                    ex[8]  = __builtin_amdgcn_exp2f(D2.x);
                    ex[9]  = __builtin_amdgcn_exp2f(D2.y);
                    ex[10] = __builtin_amdgcn_exp2f(D2.z);
                    ex[11] = __builtin_amdgcn_exp2f(D2.w);
                    ex[12] = __builtin_amdgcn_exp2f(D3.x);
                    ex[13] = __builtin_amdgcn_exp2f(D3.y);
                    ex[14] = __builtin_amdgcn_exp2f(D3.z);
                    ex[15] = __builtin_amdgcn_exp2f(D3.w);
                    #pragma unroll
                    for (int t2 = 0; t2 < 8; ++t2) {
                        f2 ee = f2{ex[2 * t2], ex[2 * t2 + 1]};
                        KA0[t2] *= ee;
                        KB0[t2] *= ee;
                    }
                }
                {
                    const float4* dv = (const float4*)(&spv1[h * 32 + q * 16]);
                    float4 D0 = dv[0], D1 = dv[1], D2 = dv[2], D3 = dv[3];
                    float ex[16];
                    ex[0]  = __builtin_amdgcn_exp2f(D0.x);
                    ex[1]  = __builtin_amdgcn_exp2f(D0.y);
                    ex[2]  = __builtin_amdgcn_exp2f(D0.z);
                    ex[3]  = __builtin_amdgcn_exp2f(D0.w);
                    ex[4]  = __builtin_amdgcn_exp2f(D1.x);
                    ex[5]  = __builtin_amdgcn_exp2f(D1.y);
                    ex[6]  = __builtin_amdgcn_exp2f(D1.z);
                    ex[7]  = __builtin_amdgcn_exp2f(D1.w);
                    ex[8]  = __builtin_amdgcn_exp2f(D2.x);
                    ex[9]  = __builtin_amdgcn_exp2f(D2.y);
                    ex[10] = __builtin_amdgcn_exp2f(D2.z);
                    ex[11] = __builtin_amdgcn_exp2f(D2.w);
                    ex[12] = __builtin_amdgcn_exp2f(D3.x);
                    ex[13] = __builtin_amdgcn_exp2f(D3.y);
                    ex[14] = __builtin_amdgcn_exp2f(D3.z);
                    ex[15] = __builtin_amdgcn_exp2f(D3.w);
                    #pragma unroll
                    for (int t2 = 0; t2 < 8; ++t2) {
                        f2 ee = f2{ex[2 * t2], ex[2 * t2 + 1]};
                        KA1[t2] *= ee;
                        KB1[t2] *= ee;
                    }
                }
                E0 = __builtin_amdgcn_exp2f(-pp0);
                E1 = __builtin_amdgcn_exp2f(-pp1);
                w0c = 1.0f;
                w1c = 1.0f;
                swv0[lane] = 1.0f;
                swv1[lane] = 1.0f;
            }
        }

        // z99 = pp + log2(wprev), z100 = pp + log2(wcur); cost = eps*ln2*sum/32
        float zs0 = 2.0f * pp0 + __builtin_amdgcn_logf(w0p)
                  + __builtin_amdgcn_logf(w0c);
        float zs1 = 2.0f * pp1 + __builtin_amdgcn_logf(w1p)
                  + __builtin_amdgcn_logf(w1c);
        #pragma unroll
        for (int off = 16; off > 0; off >>= 1) {
            zs0 += __shfl_xor(zs0, off);
            zs1 += __shfl_xor(zs1, off);
        }
        if (i == 0) {
            unsafeAtomicAdd(&dist[P0],     -0.5f * (zs0 * (EPS_F * LN2_F / 32.0f)));
            unsafeAtomicAdd(&dist[P0 + 1], -0.5f * (zs1 * (EPS_F * LN2_F / 32.0f)));
        }
    } else {
        // ============ off-diagonal path: half-wave per pair ============
        int h = lane >> 5, l = lane & 31;
        int p = (blockIdx.x - 2048) * 4 + w * 2 + h;   // 2048*4 = 8192 pairs

        float* base = S + h * 640;
        float* sX = base;
        float* sY = base + 256;
        float* sf = base + 512;
        float* sg = base + 544;
        float* su = base + 576;
        float* sv = base + 608;

        {
            const float4* zx = (const float4*)(Z + (size_t)p * 256);
            const float4* zy = (const float4*)(Z + (size_t)(N_PAIRS + p) * 256);
            *(float4*)(&sX[l * 8])     = zx[l * 2];
            *(float4*)(&sX[l * 8 + 4]) = zx[l * 2 + 1];
            *(float4*)(&sY[l * 8])     = zy[l * 2];
            *(float4*)(&sY[l * 8 + 4]) = zy[l * 2 + 1];
        }
        sg[l] = 0.0f;

        // Crow[j] = C2[l][j]; Ccol[i] = C2[i][l]
        f2 Crow[16], Ccol[16];
        {
            const f2* xp = (const f2*)(&sX[l * 8]);
            f2 x0 = xp[0], x1 = xp[1], x2 = xp[2], x3 = xp[3];
            const f2* yp = (const f2*)(&sY[l * 8]);
            f2 y0 = yp[0], y1 = yp[1], y2 = yp[2], y3 = yp[3];
            #pragma unroll
            for (int t = 0; t < 32; ++t) {
                const f2* op = (const f2*)(&sY[t * 8]);
                f2 d, s2;
                d = x0 - op[0]; s2 = d * d;
                d = x1 - op[1]; s2 = __builtin_elementwise_fma(d, d, s2);
                d = x2 - op[2]; s2 = __builtin_elementwise_fma(d, d, s2);
                d = x3 - op[3]; s2 = __builtin_elementwise_fma(d, d, s2);
                float d2 = s2.x + s2.y + 1e-12f;
                Crow[t >> 1][t & 1] = fmaf(__builtin_amdgcn_sqrtf(d2), CSCALE, CBIAS);
                const f2* qp = (const f2*)(&sX[t * 8]);
                d = qp[0] - y0; s2 = d * d;
                d = qp[1] - y1; s2 = __builtin_elementwise_fma(d, d, s2);
                d = qp[2] - y2; s2 = __builtin_elementwise_fma(d, d, s2);
                d = qp[3] - y3; s2 = __builtin_elementwise_fma(d, d, s2);
                float e2 = s2.x + s2.y + 1e-12f;
                Ccol[t >> 1][t & 1] = fmaf(__builtin_amdgcn_sqrtf(e2), CSCALE, CBIAS);
            }
        }

        float ft = 0.0f, gt = 0.0f;

        // Phase A: 2 log-domain iterations (full 32-wide LSE per lane, no shfl)
        #pragma unroll 1
        for (int it = 0; it < 2; ++it) {
            {
                const float4* gp = (const float4*)sg;
                float4 G[8];
                #pragma unroll
                for (int r = 0; r < 8; ++r) G[r] = gp[r];
                f2 val[16], m2 = f2{-1e30f, -1e30f};
                #pragma unroll
                for (int r = 0; r < 8; ++r) {
                    val[2 * r]     = f2{G[r].x, G[r].y} + Crow[2 * r];
                    val[2 * r + 1] = f2{G[r].z, G[r].w} + Crow[2 * r + 1];
                    m2 = __builtin_elementwise_max(m2, val[2 * r]);
                    m2 = __builtin_elementwise_max(m2, val[2 * r + 1]);
                }
                float m = fmaxf(m2.x, m2.y);
                f2 mm = f2{m, m};
                float s0 = 0.0f, s1 = 0.0f;
                #pragma unroll
                for (int t2 = 0; t2 < 16; ++t2) {
                    f2 e = val[t2] - mm;
                    s0 += __builtin_amdgcn_exp2f(e.x);
                    s1 += __builtin_amdgcn_exp2f(e.y);
                }
                ft = -(m + __builtin_amdgcn_logf(s0 + s1));
            }
            sf[l] = ft;
            {
                const float4* fp = (const float4*)sf;
                float4 F[8];
                #pragma unroll
                for (int r = 0; r < 8; ++r) F[r] = fp[r];
                f2 val[16], m2 = f2{-1e30f, -1e30f};
                #pragma unroll
                for (int r = 0; r < 8; ++r) {
                    val[2 * r]     = f2{F[r].x, F[r].y} + Ccol[2 * r];
                    val[2 * r + 1] = f2{F[r].z, F[r].w} + Ccol[2 * r + 1];
                    m2 = __builtin_elementwise_max(m2, val[2 * r]);
                    m2 = __builtin_elementwise_max(m2, val[2 * r + 1]);
                }
                float m = fmaxf(m2.x, m2.y);
                f2 mm = f2{m, m};
                float s0 = 0.0f, s1 = 0.0f;
                #pragma unroll
                for (int t2 = 0; t2 < 16; ++t2) {
                    f2 e = val[t2] - mm;
                    s0 += __builtin_amdgcn_exp2f(e.x);
                    s1 += __builtin_amdgcn_exp2f(e.y);
                }
                gt = -(m + __builtin_amdgcn_logf(s0 + s1));
            }
            sg[l] = gt;
        }

        // Build K (row copy + col copy); C dies here.
        f2 KR[16], KC[16];
        {
            const float4* gp = (const float4*)sg;
            #pragma unroll
            for (int r = 0; r < 8; ++r) {
                float4 G = gp[r];
                f2 a0 = f2{G.x, G.y} + Crow[2 * r] + f2{ft, ft};
                f2 a1 = f2{G.z, G.w} + Crow[2 * r + 1] + f2{ft, ft};
                KR[2 * r].x     = __builtin_amdgcn_exp2f(a0.x);
                KR[2 * r].y     = __builtin_amdgcn_exp2f(a0.y);
                KR[2 * r + 1].x = __builtin_amdgcn_exp2f(a1.x);
                KR[2 * r + 1].y = __builtin_amdgcn_exp2f(a1.y);
            }
            const float4* fp = (const float4*)sf;
            #pragma unroll
            for (int r = 0; r < 8; ++r) {
                float4 F = fp[r];
                f2 a0 = f2{F.x, F.y} + Ccol[2 * r] + f2{gt, gt};
                f2 a1 = f2{F.z, F.w} + Ccol[2 * r + 1] + f2{gt, gt};
                KC[2 * r].x     = __builtin_amdgcn_exp2f(a0.x);
                KC[2 * r].y     = __builtin_amdgcn_exp2f(a0.y);
                KC[2 * r + 1].x = __builtin_amdgcn_exp2f(a1.x);
                KC[2 * r + 1].y = __builtin_amdgcn_exp2f(a1.y);
            }
        }
        sv[l] = 1.0f;
        float ureg = 1.0f, vreg = 1.0f;

        const int blens[5] = {6, 6, 12, 12, 12};   // 48 exp iters total
        #pragma unroll 1
        for (int blk = 0; blk < 5; ++blk) {
            int L = blens[blk];
            #pragma unroll 2
            for (int s6 = 0; s6 < L; ++s6) {
                // f-step: u_l = 1/(KR . v), full dot, no shfl
                {
                    const float4* vp = (const float4*)sv;
                    f2 acc0, acc1;
                    float4 A = vp[0];
                    acc0 = KR[0] * f2{A.x, A.y};
                    acc1 = KR[1] * f2{A.z, A.w};
                    #pragma unroll
                    for (int r = 1; r < 8; ++r) {
                        float4 B = vp[r];
                        acc0 = __builtin_elementwise_fma(KR[2 * r],     f2{B.x, B.y}, acc0);
                        acc1 = __builtin_elementwise_fma(KR[2 * r + 1], f2{B.z, B.w}, acc1);
                    }
                    f2 a = acc0 + acc1;
                    ureg = __builtin_amdgcn_rcpf(a.x + a.y);
                }
                su[l] = ureg;
                // g-step: v_l = 1/(KC . u)
                {
                    const float4* up = (const float4*)su;
                    f2 acc0, acc1;
                    float4 A = up[0];
                    acc0 = KC[0] * f2{A.x, A.y};
                    acc1 = KC[1] * f2{A.z, A.w};
                    #pragma unroll
                    for (int r = 1; r < 8; ++r) {
                        float4 B = up[r];
                        acc0 = __builtin_elementwise_fma(KC[2 * r],     f2{B.x, B.y}, acc0);
                        acc1 = __builtin_elementwise_fma(KC[2 * r + 1], f2{B.z, B.w}, acc1);
                    }
                    f2 a = acc0 + acc1;
                    vreg = __builtin_amdgcn_rcpf(a.x + a.y);
                }
                sv[l] = vreg;
            }
            if (blk < 4) {
                float df = __builtin_amdgcn_logf(ureg);
                float dg = __builtin_amdgcn_logf(vreg);
                ft += df;
                gt += dg;
                sf[l] = df;
                sg[l] = dg;
                // KR[j] *= exp2(df + dg_j); KC[i] *= exp2(dg + df_i)
                const float4* dgv = (const float4*)sg;
                #pragma unroll
                for (int r = 0; r < 8; ++r) {
                    float4 D = dgv[r];
                    f2 e0, e1;
                    e0.x = __builtin_amdgcn_exp2f(df + D.x);
                    e0.y = __builtin_amdgcn_exp2f(df + D.y);
                    e1.x = __builtin_amdgcn_exp2f(df + D.z);
                    e1.y = __builtin_amdgcn_exp2f(df + D.w);
                    KR[2 * r]     *= e0;
                    KR[2 * r + 1] *= e1;
                }
                const float4* dfv = (const float4*)sf;
                #pragma unroll
                for (int r = 0; r < 8; ++r) {
                    float4 D = dfv[r];
                    f2 e0, e1;
                    e0.x = __builtin_amdgcn_exp2f(dg + D.x);
                    e0.y = __builtin_amdgcn_exp2f(dg + D.y);
                    e1.x = __builtin_amdgcn_exp2f(dg + D.z);
                    e1.y = __builtin_amdgcn_exp2f(dg + D.w);
                    KC[2 * r]     *= e0;
                    KC[2 * r + 1] *= e1;
                }
                sv[l] = 1.0f;
                ureg = 1.0f;
                vreg = 1.0f;
            }
        }
        ft += __builtin_amdgcn_logf(ureg);
        gt += __builtin_amdgcn_logf(vreg);

        // OT = eps*ln2*(sum_l f_l + g_l)/32; reduce within half-wave
        float v = ft + gt;
        #pragma unroll
        for (int off = 16; off > 0; off >>= 1) v += __shfl_xor(v, off);
        if (l == 0) {
            float cost = v * (EPS_F * LN2_F / 32.0f);
            unsafeAtomicAdd(&dist[p], cost);
        }
    }

    // ---------------- fused finalize: last block reduces dist ----------------
    __syncthreads();
    if (threadIdx.x == 0) {
        __threadfence();   // make this block's dist atomics visible device-wide
        int old = __hip_atomic_fetch_add(done, 1, __ATOMIC_ACQ_REL,
                                         __HIP_MEMORY_SCOPE_AGENT);
        is_last = (old == SINK_BLOCKS - 1) ? 1 : 0;
    }
    __syncthreads();
    if (is_last) {
        float* red = &smem[0][0];
        float s = 0.0f;
        for (int i2 = threadIdx.x; i2 < N_PAIRS; i2 += 128) {
            float d = __hip_atomic_load(&dist[i2], __ATOMIC_RELAXED,
                                        __HIP_MEMORY_SCOPE_AGENT);
            float g = gd[i2];
            s += fabsf(d - g) / g;
        }
        red[threadIdx.x] = s;
        __syncthreads();
        for (int o = 64; o > 0; o >>= 1) {
            if (threadIdx.x < o) red[threadIdx.x] += red[threadIdx.x + o];
            __syncthreads();
        }
        if (threadIdx.x == 0) out[0] = red[0] * (1.0f / N_PAIRS);
    }
}

// -------------------------------------------------------------------- launch
extern "C" void kernel_launch(void* const* d_in, const int* in_sizes, int n_in,
                              void* d_out, int out_size, void* d_ws, size_t ws_size,
                              hipStream_t stream) {
    const float* x    = (const float*)d_in[0];   // [50000,128]
    const float* W    = (const float*)d_in[1];   // [128,256]
    const int*   eidx = (const int*)d_in[2];     // [2,800000]
    const int*   pair = (const int*)d_in[3];     // [2,8192] flat = 16384 slots
    const float* gd   = (const float*)d_in[4];   // [8192]

    char* ws = (char*)d_ws;
    size_t off = 0;
    int*   cnt    = (int*)  (ws + off); off += (size_t)N_NODES * 4;
    float* dist   = (float*)(ws + off); off += (size_t)N_PAIRS * 4;
    int*   done   = (int*)  (ws + off); off += 128;
    size_t zero_bytes = off;                     // cnt+dist+done contiguous
    int*   bucket = (int*)  (ws + off); off += (size_t)N_NODES * CAP * 4; // 12.8 MB
    float* Z      = (float*)(ws + off); off += (size_t)N_SLOTS * 256 * 4; // 16.8 MB

    hipMemsetAsync(d_ws, 0, zero_bytes, stream);
    k_scatter <<<N_EDGES / 256, 256, 0, stream>>>(eidx, cnt, bucket);
    k_gemm    <<<N_SLOTS / 16, 256, 0, stream>>>(pair, x, cnt, bucket, W, Z);
    k_sinkhorn<<<SINK_BLOCKS, 128, 0, stream>>>(Z, dist, done, gd, (float*)d_out);
}

// Round 6
// 271.573 us; speedup vs baseline: 1.2237x; 1.2237x over previous
//
#include <hip/hip_runtime.h>

#define N_NODES 50000
#define N_EDGES 800000
#define N_PAIRS 8192
#define N_SLOTS (2 * N_PAIRS)
#define CAP     64          // per-node bucket capacity; P(deg>63)~5e-19

// Sinkhorn constants (log2 domain):
//   C2 = -(C/eps + ln32)*log2e ; potentials kept in /(eps*ln2) units
#define INV_EPS   20.0f
#define LOG2E_F   1.4426950408889634f
#define LN2_F     0.6931471805599453f
#define LN32_F    3.4657359027997265f
#define EPS_F     0.05f

typedef float f2 __attribute__((ext_vector_type(2)));

// ---------------------------------------- scatter into fixed-cap buckets
// Unconditional: buckets for non-pair nodes are written but never read.
__global__ __launch_bounds__(256) void k_scatter(
        const int* __restrict__ eidx,
        int* __restrict__ cnt, int* __restrict__ bucket) {
    int t = blockIdx.x * 256 + threadIdx.x;   // exact grid: 800000/256
    int dst = eidx[N_EDGES + t];
    int pos = atomicAdd(&cnt[dst], 1);
    if (pos < CAP) bucket[dst * CAP + pos] = eidx[t];
}

// ------------------------------------ fused gather + GEMM + relu
__global__ __launch_bounds__(256) void k_gemm(
        const int* __restrict__ pairs, const float* __restrict__ x,
        const int* __restrict__ cnt, const int* __restrict__ bucket,
        const float* __restrict__ W, float* __restrict__ Z) {
    __shared__ __align__(16) float Us[16 * 128];
    int sbase = blockIdx.x * 16;
    int t = threadIdx.x;
    int wave = t >> 6, lane = t & 63;

    #pragma unroll
    for (int rr = 0; rr < 4; ++rr) {
        int r = wave * 4 + rr;
        int node = pairs[sbase + r];
        int n = cnt[node];
        int m = (n < CAP) ? n : CAP;
        const int* bk = bucket + node * CAP;
        float ax = 0.0f, ay = 0.0f;
        int k = 0;
        for (; k + 4 <= m; k += 4) {
            int s0 = bk[k], s1 = bk[k + 1], s2 = bk[k + 2], s3 = bk[k + 3];
            float2 v0 = *(const float2*)(x + (size_t)s0 * 128 + lane * 2);
            float2 v1 = *(const float2*)(x + (size_t)s1 * 128 + lane * 2);
            float2 v2 = *(const float2*)(x + (size_t)s2 * 128 + lane * 2);
            float2 v3 = *(const float2*)(x + (size_t)s3 * 128 + lane * 2);
            ax += (v0.x + v1.x) + (v2.x + v3.x);
            ay += (v0.y + v1.y) + (v2.y + v3.y);
        }
        for (; k < m; ++k) {
            int s0 = bk[k];
            float2 v0 = *(const float2*)(x + (size_t)s0 * 128 + lane * 2);
            ax += v0.x;
            ay += v0.y;
        }
        float rdeg = 1.0f / fmaxf((float)n, 1.0f);
        float2 xv = *(const float2*)(x + (size_t)node * 128 + lane * 2);
        float2 o;
        o.x = fmaf(ax, rdeg, xv.x);
        o.y = fmaf(ay, rdeg, xv.y);
        *(float2*)(Us + r * 128 + lane * 2) = o;
    }
    __syncthreads();

    int jq = t & 63;   // column quad: cols 4*jq..4*jq+3
    int rq = t >> 6;   // row quad group: rows 4*rq..4*rq+3
    float acc[4][4] = {};
    const float4* Wv = (const float4*)W;   // W[128][256]

    for (int k4 = 0; k4 < 32; ++k4) {
        float4 wv[4];
        #pragma unroll
        for (int i = 0; i < 4; ++i) wv[i] = Wv[(size_t)(k4 * 4 + i) * 64 + jq];
        #pragma unroll
        for (int r = 0; r < 4; ++r) {
            float4 uv = *(const float4*)(Us + (rq * 4 + r) * 128 + k4 * 4);
            float uk0 = uv.x, uk1 = uv.y, uk2 = uv.z, uk3 = uv.w;
            acc[r][0] = fmaf(uk0, wv[0].x, acc[r][0]);
            acc[r][1] = fmaf(uk0, wv[0].y, acc[r][1]);
            acc[r][2] = fmaf(uk0, wv[0].z, acc[r][2]);
            acc[r][3] = fmaf(uk0, wv[0].w, acc[r][3]);
            acc[r][0] = fmaf(uk1, wv[1].x, acc[r][0]);
            acc[r][1] = fmaf(uk1, wv[1].y, acc[r][1]);
            acc[r][2] = fmaf(uk1, wv[1].z, acc[r][2]);
            acc[r][3] = fmaf(uk1, wv[1].w, acc[r][3]);
            acc[r][0] = fmaf(uk2, wv[2].x, acc[r][0]);
            acc[r][1] = fmaf(uk2, wv[2].y, acc[r][1]);
            acc[r][2] = fmaf(uk2, wv[2].z, acc[r][2]);
            acc[r][3] = fmaf(uk2, wv[2].w, acc[r][3]);
            acc[r][0] = fmaf(uk3, wv[3].x, acc[r][0]);
            acc[r][1] = fmaf(uk3, wv[3].y, acc[r][1]);
            acc[r][2] = fmaf(uk3, wv[3].z, acc[r][2]);
            acc[r][3] = fmaf(uk3, wv[3].w, acc[r][3]);
        }
    }

    #pragma unroll
    for (int r = 0; r < 4; ++r) {
        float4 o;
        o.x = fmaxf(acc[r][0], 0.0f);
        o.y = fmaxf(acc[r][1], 0.0f);
        o.z = fmaxf(acc[r][2], 0.0f);
        o.w = fmaxf(acc[r][3], 0.0f);
        *(float4*)(Z + (size_t)(sbase + rq * 4 + r) * 256 + jq * 4) = o;
    }
}

// ------------------------------------------------------------------- sinkhorn
// 128-thread blocks (2 waves), no __syncthreads anywhere.
//  blocks [0,2048):    diagonal — one wave per TWO pairs (dual-chain ILP).
//  blocks [2048,4096): off-diagonal — HALF-WAVE per pair (2 pairs/wave).
__global__ __launch_bounds__(128) void k_sinkhorn(
        const float* __restrict__ Z, float* __restrict__ dist) {
    __shared__ __align__(16) float smem[2][1280];   // 10240 B

    int w = threadIdx.x >> 6;
    int lane = threadIdx.x & 63;
    float* S = &smem[w][0];
    const float CSCALE = -INV_EPS * LOG2E_F;
    const float CBIAS  = -LN32_F * LOG2E_F;

    if (blockIdx.x < 2048) {
        // ==== diagonal path: 2 pairs/wave, dual independent chains ====
        int h = lane >> 5, i = lane & 31;
        int q = (i >> 4) & 1;                 // k-half this lane reads
        int ip = i ^ 16;                      // partner row
        int P0 = blockIdx.x * 4 + w * 2;      // 2048*2*2 = 8192 pairs

        float* sP   = S;                      // 512 floats, transient per build
        float* swv0 = S + 512;
        float* spv0 = S + 576;
        float* swv1 = S + 640;
        float* spv1 = S + 704;

        f2 KA0[8], KB0[8], KA1[8], KB1[8];

        auto build = [&](f2 (&KA)[8], f2 (&KB)[8], int P) {
            int src = h ? (N_PAIRS + P) : P;
            float* sPh = sP + h * 256;
            {
                const float4* zp = (const float4*)(Z + (size_t)src * 256);
                *(float4*)(&sPh[i * 8])     = zp[i * 2];
                *(float4*)(&sPh[i * 8 + 4]) = zp[i * 2 + 1];
            }
            const f2* xp = (const f2*)(&sPh[i * 8]);
            f2 x0 = xp[0], x1 = xp[1], x2 = xp[2], x3 = xp[3];
            const f2* bp = (const f2*)(&sPh[ip * 8]);
            f2 b0 = bp[0], b1 = bp[1], b2 = bp[2], b3 = bp[3];
            #pragma unroll
            for (int t = 0; t < 16; ++t) {
                int j = q * 16 + t;
                const f2* yp = (const f2*)(&sPh[j * 8]);
                f2 y0 = yp[0], y1 = yp[1], y2 = yp[2], y3 = yp[3];
                f2 d, s2;
                d = x0 - y0; s2 = d * d;
                d = x1 - y1; s2 = __builtin_elementwise_fma(d, d, s2);
                d = x2 - y2; s2 = __builtin_elementwise_fma(d, d, s2);
                d = x3 - y3; s2 = __builtin_elementwise_fma(d, d, s2);
                float d2 = s2.x + s2.y + 1e-12f;
                KA[t >> 1][t & 1] = __builtin_amdgcn_exp2f(
                    fmaf(__builtin_amdgcn_sqrtf(d2), CSCALE, CBIAS));
                d = b0 - y0; s2 = d * d;
                d = b1 - y1; s2 = __builtin_elementwise_fma(d, d, s2);
                d = b2 - y2; s2 = __builtin_elementwise_fma(d, d, s2);
                d = b3 - y3; s2 = __builtin_elementwise_fma(d, d, s2);
                float e2 = s2.x + s2.y + 1e-12f;
                KB[t >> 1][t & 1] = __builtin_amdgcn_exp2f(
                    fmaf(__builtin_amdgcn_sqrtf(e2), CSCALE, CBIAS));
            }
        };
        build(KA0, KB0, P0);
        build(KA1, KB1, P0 + 1);

        float pp0 = 0.0f, pp1 = 0.0f, E0 = 1.0f, E1 = 1.0f;
        float w0c = 1.0f, w0p = 1.0f, w1c = 1.0f, w1p = 1.0f;
        swv0[lane] = 1.0f;
        swv1[lane] = 1.0f;

        const int blens[9] = {4, 12, 12, 12, 12, 12, 12, 12, 12};  // 100 T-steps
        #pragma unroll 1
        for (int blk = 0; blk < 9; ++blk) {
            int L = blens[blk];
            #pragma unroll 1
            for (int s = 0; s < L; ++s) {
                const float4* wp0 = (const float4*)(&swv0[h * 32 + q * 16]);
                const float4* wp1 = (const float4*)(&swv1[h * 32 + q * 16]);
                float4 A0 = wp0[0], A1 = wp0[1], A2 = wp0[2], A3 = wp0[3];
                float4 B0 = wp1[0], B1 = wp1[1], B2 = wp1[2], B3 = wp1[3];
                // ---- chain 0 dot ----
                f2 aA0 = KA0[0] * f2{A0.x, A0.y};
                f2 aA1 = KA0[1] * f2{A0.z, A0.w};
                f2 aB0 = KB0[0] * f2{A0.x, A0.y};
                f2 aB1 = KB0[1] * f2{A0.z, A0.w};
                aA0 = __builtin_elementwise_fma(KA0[2], f2{A1.x, A1.y}, aA0);
                aA1 = __builtin_elementwise_fma(KA0[3], f2{A1.z, A1.w}, aA1);
                aB0 = __builtin_elementwise_fma(KB0[2], f2{A1.x, A1.y}, aB0);
                aB1 = __builtin_elementwise_fma(KB0[3], f2{A1.z, A1.w}, aB1);
                aA0 = __builtin_elementwise_fma(KA0[4], f2{A2.x, A2.y}, aA0);
                aA1 = __builtin_elementwise_fma(KA0[5], f2{A2.z, A2.w}, aA1);
                aB0 = __builtin_elementwise_fma(KB0[4], f2{A2.x, A2.y}, aB0);
                aB1 = __builtin_elementwise_fma(KB0[5], f2{A2.z, A2.w}, aB1);
                aA0 = __builtin_elementwise_fma(KA0[6], f2{A3.x, A3.y}, aA0);
                aA1 = __builtin_elementwise_fma(KA0[7], f2{A3.z, A3.w}, aA1);
                aB0 = __builtin_elementwise_fma(KB0[6], f2{A3.x, A3.y}, aB0);
                aB1 = __builtin_elementwise_fma(KB0[7], f2{A3.z, A3.w}, aB1);
                f2 aa0 = aA0 + aA1;
                f2 bb0 = aB0 + aB1;
                float pa0 = aa0.x + aa0.y;
                float pb0 = bb0.x + bb0.y;
                // ---- chain 1 dot ----
                f2 cA0 = KA1[0] * f2{B0.x, B0.y};
                f2 cA1 = KA1[1] * f2{B0.z, B0.w};
                f2 cB0 = KB1[0] * f2{B0.x, B0.y};
                f2 cB1 = KB1[1] * f2{B0.z, B0.w};
                cA0 = __builtin_elementwise_fma(KA1[2], f2{B1.x, B1.y}, cA0);
                cA1 = __builtin_elementwise_fma(KA1[3], f2{B1.z, B1.w}, cA1);
                cB0 = __builtin_elementwise_fma(KB1[2], f2{B1.x, B1.y}, cB0);
                cB1 = __builtin_elementwise_fma(KB1[3], f2{B1.z, B1.w}, cB1);
                cA0 = __builtin_elementwise_fma(KA1[4], f2{B2.x, B2.y}, cA0);
                cA1 = __builtin_elementwise_fma(KA1[5], f2{B2.z, B2.w}, cA1);
                cB0 = __builtin_elementwise_fma(KB1[4], f2{B2.x, B2.y}, cB0);
                cB1 = __builtin_elementwise_fma(KB1[5], f2{B2.z, B2.w}, cB1);
                cA0 = __builtin_elementwise_fma(KA1[6], f2{B3.x, B3.y}, cA0);
                cA1 = __builtin_elementwise_fma(KA1[7], f2{B3.z, B3.w}, cA1);
                cB0 = __builtin_elementwise_fma(KB1[6], f2{B3.x, B3.y}, cB0);
                cB1 = __builtin_elementwise_fma(KB1[7], f2{B3.z, B3.w}, cB1);
                f2 aa1 = cA0 + cA1;
                f2 bb1 = cB0 + cB1;
                float pa1 = aa1.x + aa1.y;
                float pb1 = bb1.x + bb1.y;
                // combine + update, both chains
                float o0 = __shfl_xor(pb0, 16);
                float o1 = __shfl_xor(pb1, 16);
                w0p = w0c;
                w0c = __builtin_amdgcn_rcpf(pa0 + o0) * E0;
                w1p = w1c;
                w1c = __builtin_amdgcn_rcpf(pa1 + o1) * E1;
                swv0[h * 32 + i] = w0c;
                swv1[h * 32 + i] = w1c;
            }
            if (blk < 8) {
                float d0 = __builtin_amdgcn_logf(w0c);
                float d1 = __builtin_amdgcn_logf(w1c);
                pp0 += d0;
                pp1 += d1;
                spv0[h * 32 + i] = d0;
                spv1[h * 32 + i] = d1;
                {
                    const float4* dv = (const float4*)(&spv0[h * 32 + q * 16]);
                    float4 D0 = dv[0], D1 = dv[1], D2 = dv[2], D3 = dv[3];
                    float ex[16];
                    ex[0]  = __builtin_amdgcn_exp2f(D0.x);
                    ex[1]  = __builtin_amdgcn_exp2f(D0.y);
                    ex[2]  = __builtin_amdgcn_exp2f(D0.z);
                    ex[3]  = __builtin_amdgcn_exp2f(D0.w);
                    ex[4]  = __builtin_amdgcn_exp2f(D1.x);
                    ex[5]  = __builtin_amdgcn_exp2f(D1.y);
                    ex[6]  = __builtin_amdgcn_exp2f(D1.z);
                    ex[7]  = __builtin_amdgcn_exp2f(D1.w);
                    ex[8]  = __builtin_amdgcn_exp2f(D2.x);
                    ex[9]  = __builtin_amdgcn_exp2f(D2.y);
                    ex[10] = __builtin_amdgcn_exp2f(D2.z);
                    ex[11] = __builtin_amdgcn_exp2f(D2.w);
                    ex[12] = __builtin_amdgcn_exp2f(D3.x);
                    ex[13] = __builtin_amdgcn_exp2f(D3.y);
                    ex[14] = __builtin_amdgcn_exp2f(D3.z);
                    ex[15] = __builtin_amdgcn_exp2f(D3.w);
                    #pragma unroll
                    for (int t2 = 0; t2 < 8; ++t2) {
                        f2 ee = f2{ex[2 * t2], ex[2 * t2 + 1]};
                        KA0[t2] *= ee;
                        KB0[t2] *= ee;
                    }
                }
                {
                    const float4* dv = (const float4*)(&spv1[h * 32 + q * 16]);
                    float4 D0 = dv[0], D1 = dv[1], D2 = dv[2], D3 = dv[3];
                    float ex[16];
                    ex[0]  = __builtin_amdgcn_exp2f(D0.x);
                    ex[1]  = __builtin_amdgcn_exp2f(D0.y);
                    ex[2]  = __builtin_amdgcn_exp2f(D0.z);
                    ex[3]  = __builtin_amdgcn_exp2f(D0.w);
                    ex[4]  = __builtin_amdgcn_exp2f(D1.x);
                    ex[5]  = __builtin_amdgcn_exp2f(D1.y);
                    ex[6]  = __builtin_amdgcn_exp2f(D1.z);
                    ex[7]  = __builtin_amdgcn_exp2f(D1.w);
                    ex[8]  = __builtin_amdgcn_exp2f(D2.x);
                    ex[9]  = __builtin_amdgcn_exp2f(D2.y);
                    ex[10] = __builtin_amdgcn_exp2f(D2.z);
                    ex[11] = __builtin_amdgcn_exp2f(D2.w);
                    ex[12] = __builtin_amdgcn_exp2f(D3.x);
                    ex[13] = __builtin_amdgcn_exp2f(D3.y);
                    ex[14] = __builtin_amdgcn_exp2f(D3.z);
                    ex[15] = __builtin_amdgcn_exp2f(D3.w);
                    #pragma unroll
                    for (int t2 = 0; t2 < 8; ++t2) {
                        f2 ee = f2{ex[2 * t2], ex[2 * t2 + 1]};
                        KA1[t2] *= ee;
                        KB1[t2] *= ee;
                    }
                }
                E0 = __builtin_amdgcn_exp2f(-pp0);
                E1 = __builtin_amdgcn_exp2f(-pp1);
                w0c = 1.0f;
                w1c = 1.0f;
                swv0[lane] = 1.0f;
                swv1[lane] = 1.0f;
            }
        }

        // z99 = pp + log2(wprev), z100 = pp + log2(wcur); cost = eps*ln2*sum/32
        float zs0 = 2.0f * pp0 + __builtin_amdgcn_logf(w0p)
                  + __builtin_amdgcn_logf(w0c);
        float zs1 = 2.0f * pp1 + __builtin_amdgcn_logf(w1p)
                  + __builtin_amdgcn_logf(w1c);
        #pragma unroll
        for (int off = 16; off > 0; off >>= 1) {
            zs0 += __shfl_xor(zs0, off);
            zs1 += __shfl_xor(zs1, off);
        }
        if (i == 0) {
            unsafeAtomicAdd(&dist[P0],     -0.5f * (zs0 * (EPS_F * LN2_F / 32.0f)));
            unsafeAtomicAdd(&dist[P0 + 1], -0.5f * (zs1 * (EPS_F * LN2_F / 32.0f)));
        }
    } else {
        // ============ off-diagonal path: half-wave per pair ============
        int h = lane >> 5, l = lane & 31;
        int p = (blockIdx.x - 2048) * 4 + w * 2 + h;   // 2048*4 = 8192 pairs

        float* base = S + h * 640;
        float* sX = base;
        float* sY = base + 256;
        float* sf = base + 512;
        float* sg = base + 544;
        float* su = base + 576;
        float* sv = base + 608;

        {
            const float4* zx = (const float4*)(Z + (size_t)p * 256);
            const float4* zy = (const float4*)(Z + (size_t)(N_PAIRS + p) * 256);
            *(float4*)(&sX[l * 8])     = zx[l * 2];
            *(float4*)(&sX[l * 8 + 4]) = zx[l * 2 + 1];
            *(float4*)(&sY[l * 8])     = zy[l * 2];
            *(float4*)(&sY[l * 8 + 4]) = zy[l * 2 + 1];
        }
        sg[l] = 0.0f;

        // Crow[j] = C2[l][j]; Ccol[i] = C2[i][l]
        f2 Crow[16], Ccol[16];
        {
            const f2* xp = (const f2*)(&sX[l * 8]);
            f2 x0 = xp[0], x1 = xp[1], x2 = xp[2], x3 = xp[3];
            const f2* yp = (const f2*)(&sY[l * 8]);
            f2 y0 = yp[0], y1 = yp[1], y2 = yp[2], y3 = yp[3];
            #pragma unroll
            for (int t = 0; t < 32; ++t) {
                const f2* op = (const f2*)(&sY[t * 8]);
                f2 d, s2;
                d = x0 - op[0]; s2 = d * d;
                d = x1 - op[1]; s2 = __builtin_elementwise_fma(d, d, s2);
                d = x2 - op[2]; s2 = __builtin_elementwise_fma(d, d, s2);
                d = x3 - op[3]; s2 = __builtin_elementwise_fma(d, d, s2);
                float d2 = s2.x + s2.y + 1e-12f;
                Crow[t >> 1][t & 1] = fmaf(__builtin_amdgcn_sqrtf(d2), CSCALE, CBIAS);
                const f2* qp = (const f2*)(&sX[t * 8]);
                d = qp[0] - y0; s2 = d * d;
                d = qp[1] - y1; s2 = __builtin_elementwise_fma(d, d, s2);
                d = qp[2] - y2; s2 = __builtin_elementwise_fma(d, d, s2);
                d = qp[3] - y3; s2 = __builtin_elementwise_fma(d, d, s2);
                float e2 = s2.x + s2.y + 1e-12f;
                Ccol[t >> 1][t & 1] = fmaf(__builtin_amdgcn_sqrtf(e2), CSCALE, CBIAS);
            }
        }

        float ft = 0.0f, gt = 0.0f;

        // Phase A: 2 log-domain iterations (full 32-wide LSE per lane, no shfl)
        #pragma unroll 1
        for (int it = 0; it < 2; ++it) {
            {
                const float4* gp = (const float4*)sg;
                float4 G[8];
                #pragma unroll
                for (int r = 0; r < 8; ++r) G[r] = gp[r];
                f2 val[16], m2 = f2{-1e30f, -1e30f};
                #pragma unroll
                for (int r = 0; r < 8; ++r) {
                    val[2 * r]     = f2{G[r].x, G[r].y} + Crow[2 * r];
                    val[2 * r + 1] = f2{G[r].z, G[r].w} + Crow[2 * r + 1];
                    m2 = __builtin_elementwise_max(m2, val[2 * r]);
                    m2 = __builtin_elementwise_max(m2, val[2 * r + 1]);
                }
                float m = fmaxf(m2.x, m2.y);
                f2 mm = f2{m, m};
                float s0 = 0.0f, s1 = 0.0f;
                #pragma unroll
                for (int t2 = 0; t2 < 16; ++t2) {
                    f2 e = val[t2] - mm;
                    s0 += __builtin_amdgcn_exp2f(e.x);
                    s1 += __builtin_amdgcn_exp2f(e.y);
                }
                ft = -(m + __builtin_amdgcn_logf(s0 + s1));
            }
            sf[l] = ft;
            {
                const float4* fp = (const float4*)sf;
                float4 F[8];
                #pragma unroll
                for (int r = 0; r < 8; ++r) F[r] = fp[r];
                f2 val[16], m2 = f2{-1e30f, -1e30f};
                #pragma unroll
                for (int r = 0; r < 8; ++r) {
                    val[2 * r]     = f2{F[r].x, F[r].y} + Ccol[2 * r];
                    val[2 * r + 1] = f2{F[r].z, F[r].w} + Ccol[2 * r + 1];
                    m2 = __builtin_elementwise_max(m2, val[2 * r]);
                    m2 = __builtin_elementwise_max(m2, val[2 * r + 1]);
                }
                float m = fmaxf(m2.x, m2.y);
                f2 mm = f2{m, m};
                float s0 = 0.0f, s1 = 0.0f;
                #pragma unroll
                for (int t2 = 0; t2 < 16; ++t2) {
                    f2 e = val[t2] - mm;
                    s0 += __builtin_amdgcn_exp2f(e.x);
                    s1 += __builtin_amdgcn_exp2f(e.y);
                }
                gt = -(m + __builtin_amdgcn_logf(s0 + s1));
            }
            sg[l] = gt;
        }

        // Build K (row copy + col copy); C dies here.
        f2 KR[16], KC[16];
        {
            const float4* gp = (const float4*)sg;
            #pragma unroll
            for (int r = 0; r < 8; ++r) {
                float4 G = gp[r];
                f2 a0 = f2{G.x, G.y} + Crow[2 * r] + f2{ft, ft};
                f2 a1 = f2{G.z, G.w} + Crow[2 * r + 1] + f2{ft, ft};
                KR[2 * r].x     = __builtin_amdgcn_exp2f(a0.x);
                KR[2 * r].y     = __builtin_amdgcn_exp2f(a0.y);
                KR[2 * r + 1].x = __builtin_amdgcn_exp2f(a1.x);
                KR[2 * r + 1].y = __builtin_amdgcn_exp2f(a1.y);
            }
            const float4* fp = (const float4*)sf;
            #pragma unroll
            for (int r = 0; r < 8; ++r) {
                float4 F = fp[r];
                f2 a0 = f2{F.x, F.y} + Ccol[2 * r] + f2{gt, gt};
                f2 a1 = f2{F.z, F.w} + Ccol[2 * r + 1] + f2{gt, gt};
                KC[2 * r].x     = __builtin_amdgcn_exp2f(a0.x);
                KC[2 * r].y     = __builtin_amdgcn_exp2f(a0.y);
                KC[2 * r + 1].x = __builtin_amdgcn_exp2f(a1.x);
                KC[2 * r + 1].y = __builtin_amdgcn_exp2f(a1.y);
            }
        }
        sv[l] = 1.0f;
        float ureg = 1.0f, vreg = 1.0f;

        const int blens[5] = {6, 6, 12, 12, 12};   // 48 exp iters total
        #pragma unroll 1
        for (int blk = 0; blk < 5; ++blk) {
            int L = blens[blk];
            #pragma unroll 2
            for (int s6 = 0; s6 < L; ++s6) {
                // f-step: u_l = 1/(KR . v), full dot, no shfl
                {
                    const float4* vp = (const float4*)sv;
                    f2 acc0, acc1;
                    float4 A = vp[0];
                    acc0 = KR[0] * f2{A.x, A.y};
                    acc1 = KR[1] * f2{A.z, A.w};
                    #pragma unroll
                    for (int r = 1; r < 8; ++r) {
                        float4 B = vp[r];
                        acc0 = __builtin_elementwise_fma(KR[2 * r],     f2{B.x, B.y}, acc0);
                        acc1 = __builtin_elementwise_fma(KR[2 * r + 1], f2{B.z, B.w}, acc1);
                    }
                    f2 a = acc0 + acc1;
                    ureg = __builtin_amdgcn_rcpf(a.x + a.y);
                }
                su[l] = ureg;
                // g-step: v_l = 1/(KC . u)
                {
                    const float4* up = (const float4*)su;
                    f2 acc0, acc1;
                    float4 A = up[0];
                    acc0 = KC[0] * f2{A.x, A.y};
                    acc1 = KC[1] * f2{A.z, A.w};
                    #pragma unroll
                    for (int r = 1; r < 8; ++r) {
                        float4 B = up[r];
                        acc0 = __builtin_elementwise_fma(KC[2 * r],     f2{B.x, B.y}, acc0);
                        acc1 = __builtin_elementwise_fma(KC[2 * r + 1], f2{B.z, B.w}, acc1);
                    }
                    f2 a = acc0 + acc1;
                    vreg = __builtin_amdgcn_rcpf(a.x + a.y);
                }
                sv[l] = vreg;
            }
            if (blk < 4) {
                float df = __builtin_amdgcn_logf(ureg);
                float dg = __builtin_amdgcn_logf(vreg);
                ft += df;
                gt += dg;
                sf[l] = df;
                sg[l] = dg;
                // KR[j] *= exp2(df + dg_j); KC[i] *= exp2(dg + df_i)
                const float4* dgv = (const float4*)sg;
                #pragma unroll
                for (int r = 0; r < 8; ++r) {
                    float4 D = dgv[r];
                    f2 e0, e1;
                    e0.x = __builtin_amdgcn_exp2f(df + D.x);
                    e0.y = __builtin_amdgcn_exp2f(df + D.y);
                    e1.x = __builtin_amdgcn_exp2f(df + D.z);
                    e1.y = __builtin_amdgcn_exp2f(df + D.w);
                    KR[2 * r]     *= e0;
                    KR[2 * r + 1] *= e1;
                }
                const float4* dfv = (const float4*)sf;
                #pragma unroll
                for (int r = 0; r < 8; ++r) {
                    float4 D = dfv[r];
                    f2 e0, e1;
                    e0.x = __builtin_amdgcn_exp2f(dg + D.x);
                    e0.y = __builtin_amdgcn_exp2f(dg + D.y);
                    e1.x = __builtin_amdgcn_exp2f(dg + D.z);
                    e1.y = __builtin_amdgcn_exp2f(dg + D.w);
                    KC[2 * r]     *= e0;
                    KC[2 * r + 1] *= e1;
                }
                sv[l] = 1.0f;
                ureg = 1.0f;
                vreg = 1.0f;
            }
        }
        ft += __builtin_amdgcn_logf(ureg);
        gt += __builtin_amdgcn_logf(vreg);

        // OT = eps*ln2*(sum_l f_l + g_l)/32; reduce within half-wave
        float v = ft + gt;
        #pragma unroll
        for (int off = 16; off > 0; off >>= 1) v += __shfl_xor(v, off);
        if (l == 0) {
            float cost = v * (EPS_F * LN2_F / 32.0f);
            unsafeAtomicAdd(&dist[p], cost);
        }
    }
}

// ------------------------------------------------------------------ finalize
__global__ void k_finalize(const float* __restrict__ dist,
                           const float* __restrict__ gd, float* __restrict__ out) {
    __shared__ float red[256];
    float s = 0.0f;
    for (int i = threadIdx.x; i < N_PAIRS; i += 256) {
        float g = gd[i];
        s += fabsf(dist[i] - g) / g;
    }
    red[threadIdx.x] = s;
    __syncthreads();
    for (int o = 128; o > 0; o >>= 1) {
        if (threadIdx.x < o) red[threadIdx.x] += red[threadIdx.x + o];
        __syncthreads();
    }
    if (threadIdx.x == 0) out[0] = red[0] * (1.0f / N_PAIRS);
}

// -------------------------------------------------------------------- launch
extern "C" void kernel_launch(void* const* d_in, const int* in_sizes, int n_in,
                              void* d_out, int out_size, void* d_ws, size_t ws_size,
                              hipStream_t stream) {
    const float* x    = (const float*)d_in[0];   // [50000,128]
    const float* W    = (const float*)d_in[1];   // [128,256]
    const int*   eidx = (const int*)d_in[2];     // [2,800000]
    const int*   pair = (const int*)d_in[3];     // [2,8192] flat = 16384 slots
    const float* gd   = (const float*)d_in[4];   // [8192]

    char* ws = (char*)d_ws;
    size_t off = 0;
    int*   cnt    = (int*)  (ws + off); off += (size_t)N_NODES * 4;
    float* dist   = (float*)(ws + off); off += (size_t)N_PAIRS * 4;
    size_t zero_bytes = off;                     // cnt+dist contiguous
    int*   bucket = (int*)  (ws + off); off += (size_t)N_NODES * CAP * 4; // 12.8 MB
    float* Z      = (float*)(ws + off); off += (size_t)N_SLOTS * 256 * 4; // 16.8 MB

    hipMemsetAsync(d_ws, 0, zero_bytes, stream);
    k_scatter <<<N_EDGES / 256, 256, 0, stream>>>(eidx, cnt, bucket);
    k_gemm    <<<N_SLOTS / 16, 256, 0, stream>>>(pair, x, cnt, bucket, W, Z);
    k_sinkhorn<<<4096, 128, 0, stream>>>(Z, dist);
    k_finalize<<<1, 256, 0, stream>>>(dist, gd, (float*)d_out);
}

// Round 7
// 249.585 us; speedup vs baseline: 1.3315x; 1.0881x over previous
//
#include <hip/hip_runtime.h>

#define N_NODES 50000
#define N_EDGES 800000
#define N_PAIRS 8192
#define N_SLOTS (2 * N_PAIRS)
#define CAP     64          // per-node bucket capacity; P(deg>63)~5e-19

// Sinkhorn constants (log2 domain):
//   C2 = -(C/eps + ln32)*log2e ; potentials kept in /(eps*ln2) units
#define INV_EPS   20.0f
#define LOG2E_F   1.4426950408889634f
#define LN2_F     0.6931471805599453f
#define LN32_F    3.4657359027997265f
#define EPS_F     0.05f

typedef float f2 __attribute__((ext_vector_type(2)));

// ---------------------------------------------------------------- mark needed
__global__ void k_mark(const int* __restrict__ pairs, int* __restrict__ flags) {
    int t = blockIdx.x * 256 + threadIdx.x;
    if (t < N_SLOTS) flags[pairs[t]] = 1;
}

// ---------------------------------------- scatter into fixed-cap buckets
__global__ __launch_bounds__(256) void k_scatter(
        const int* __restrict__ eidx, const int* __restrict__ flags,
        int* __restrict__ cnt, int* __restrict__ bucket) {
    int t = blockIdx.x * 256 + threadIdx.x;   // exact grid: 800000/256
    int dst = eidx[N_EDGES + t];
    if (!flags[dst]) return;
    int pos = atomicAdd(&cnt[dst], 1);
    if (pos < CAP) bucket[dst * CAP + pos] = eidx[t];
}

// ------------------------------------ fused gather + GEMM + relu
__global__ __launch_bounds__(256) void k_gemm(
        const int* __restrict__ pairs, const float* __restrict__ x,
        const int* __restrict__ cnt, const int* __restrict__ bucket,
        const float* __restrict__ W, float* __restrict__ Z) {
    __shared__ __align__(16) float Us[16 * 128];
    int sbase = blockIdx.x * 16;
    int t = threadIdx.x;
    int wave = t >> 6, lane = t & 63;

    #pragma unroll
    for (int rr = 0; rr < 4; ++rr) {
        int r = wave * 4 + rr;
        int node = pairs[sbase + r];
        int n = cnt[node];
        int m = (n < CAP) ? n : CAP;
        const int* bk = bucket + node * CAP;
        float ax = 0.0f, ay = 0.0f;
        int k = 0;
        for (; k + 4 <= m; k += 4) {
            int s0 = bk[k], s1 = bk[k + 1], s2 = bk[k + 2], s3 = bk[k + 3];
            float2 v0 = *(const float2*)(x + (size_t)s0 * 128 + lane * 2);
            float2 v1 = *(const float2*)(x + (size_t)s1 * 128 + lane * 2);
            float2 v2 = *(const float2*)(x + (size_t)s2 * 128 + lane * 2);
            float2 v3 = *(const float2*)(x + (size_t)s3 * 128 + lane * 2);
            ax += (v0.x + v1.x) + (v2.x + v3.x);
            ay += (v0.y + v1.y) + (v2.y + v3.y);
        }
        for (; k < m; ++k) {
            int s0 = bk[k];
            float2 v0 = *(const float2*)(x + (size_t)s0 * 128 + lane * 2);
            ax += v0.x;
            ay += v0.y;
        }
        float rdeg = 1.0f / fmaxf((float)n, 1.0f);
        float2 xv = *(const float2*)(x + (size_t)node * 128 + lane * 2);
        float2 o;
        o.x = fmaf(ax, rdeg, xv.x);
        o.y = fmaf(ay, rdeg, xv.y);
        *(float2*)(Us + r * 128 + lane * 2) = o;
    }
    __syncthreads();

    int jq = t & 63;   // column quad: cols 4*jq..4*jq+3
    int rq = t >> 6;   // row quad group: rows 4*rq..4*rq+3
    float acc[4][4] = {};
    const float4* Wv = (const float4*)W;   // W[128][256]

    for (int k4 = 0; k4 < 32; ++k4) {
        float4 wv[4];
        #pragma unroll
        for (int i = 0; i < 4; ++i) wv[i] = Wv[(size_t)(k4 * 4 + i) * 64 + jq];
        #pragma unroll
        for (int r = 0; r < 4; ++r) {
            float4 uv = *(const float4*)(Us + (rq * 4 + r) * 128 + k4 * 4);
            float uk0 = uv.x, uk1 = uv.y, uk2 = uv.z, uk3 = uv.w;
            acc[r][0] = fmaf(uk0, wv[0].x, acc[r][0]);
            acc[r][1] = fmaf(uk0, wv[0].y, acc[r][1]);
            acc[r][2] = fmaf(uk0, wv[0].z, acc[r][2]);
            acc[r][3] = fmaf(uk0, wv[0].w, acc[r][3]);
            acc[r][0] = fmaf(uk1, wv[1].x, acc[r][0]);
            acc[r][1] = fmaf(uk1, wv[1].y, acc[r][1]);
            acc[r][2] = fmaf(uk1, wv[1].z, acc[r][2]);
            acc[r][3] = fmaf(uk1, wv[1].w, acc[r][3]);
            acc[r][0] = fmaf(uk2, wv[2].x, acc[r][0]);
            acc[r][1] = fmaf(uk2, wv[2].y, acc[r][1]);
            acc[r][2] = fmaf(uk2, wv[2].z, acc[r][2]);
            acc[r][3] = fmaf(uk2, wv[2].w, acc[r][3]);
            acc[r][0] = fmaf(uk3, wv[3].x, acc[r][0]);
            acc[r][1] = fmaf(uk3, wv[3].y, acc[r][1]);
            acc[r][2] = fmaf(uk3, wv[3].z, acc[r][2]);
            acc[r][3] = fmaf(uk3, wv[3].w, acc[r][3]);
        }
    }

    #pragma unroll
    for (int r = 0; r < 4; ++r) {
        float4 o;
        o.x = fmaxf(acc[r][0], 0.0f);
        o.y = fmaxf(acc[r][1], 0.0f);
        o.z = fmaxf(acc[r][2], 0.0f);
        o.w = fmaxf(acc[r][3], 0.0f);
        *(float4*)(Z + (size_t)(sbase + rq * 4 + r) * 256 + jq * 4) = o;
    }
}

// ------------------------------------------------------------------- sinkhorn
// 128-thread blocks (2 waves), no __syncthreads anywhere.
//  blocks [0,2048):    diagonal — one wave per TWO pairs (dual-chain ILP).
//  blocks [2048,3072): off-diagonal — 16 LANES per pair, 2 rows/lane,
//                      4 pairs/wave. Halves the LDS broadcast traffic
//                      (the dominant cost: every lane reads the full
//                      128B u/v vector per dot; 2 rows amortize it).
__global__ __launch_bounds__(128) void k_sinkhorn(
        const float* __restrict__ Z, float* __restrict__ dist) {
    __shared__ __align__(16) float smem[2][2560];   // 20480 B

    int w = threadIdx.x >> 6;
    int lane = threadIdx.x & 63;
    float* S = &smem[w][0];
    const float CSCALE = -INV_EPS * LOG2E_F;
    const float CBIAS  = -LN32_F * LOG2E_F;

    if (blockIdx.x < 2048) {
        // ==== diagonal path: 2 pairs/wave, dual independent chains ====
        int h = lane >> 5, i = lane & 31;
        int q = (i >> 4) & 1;                 // k-half this lane reads
        int ip = i ^ 16;                      // partner row
        int P0 = blockIdx.x * 4 + w * 2;      // 2048*2*2 = 8192 pairs

        float* sP   = S;                      // 512 floats, transient per build
        float* swv0 = S + 512;
        float* spv0 = S + 576;
        float* swv1 = S + 640;
        float* spv1 = S + 704;

        f2 KA0[8], KB0[8], KA1[8], KB1[8];

        auto build = [&](f2 (&KA)[8], f2 (&KB)[8], int P) {
            int src = h ? (N_PAIRS + P) : P;
            float* sPh = sP + h * 256;
            {
                const float4* zp = (const float4*)(Z + (size_t)src * 256);
                *(float4*)(&sPh[i * 8])     = zp[i * 2];
                *(float4*)(&sPh[i * 8 + 4]) = zp[i * 2 + 1];
            }
            const f2* xp = (const f2*)(&sPh[i * 8]);
            f2 x0 = xp[0], x1 = xp[1], x2 = xp[2], x3 = xp[3];
            const f2* bp = (const f2*)(&sPh[ip * 8]);
            f2 b0 = bp[0], b1 = bp[1], b2 = bp[2], b3 = bp[3];
            #pragma unroll
            for (int t = 0; t < 16; ++t) {
                int j = q * 16 + t;
                const f2* yp = (const f2*)(&sPh[j * 8]);
                f2 y0 = yp[0], y1 = yp[1], y2 = yp[2], y3 = yp[3];
                f2 d, s2;
                d = x0 - y0; s2 = d * d;
                d = x1 - y1; s2 = __builtin_elementwise_fma(d, d, s2);
                d = x2 - y2; s2 = __builtin_elementwise_fma(d, d, s2);
                d = x3 - y3; s2 = __builtin_elementwise_fma(d, d, s2);
                float d2 = s2.x + s2.y + 1e-12f;
                KA[t >> 1][t & 1] = __builtin_amdgcn_exp2f(
                    fmaf(__builtin_amdgcn_sqrtf(d2), CSCALE, CBIAS));
                d = b0 - y0; s2 = d * d;
                d = b1 - y1; s2 = __builtin_elementwise_fma(d, d, s2);
                d = b2 - y2; s2 = __builtin_elementwise_fma(d, d, s2);
                d = b3 - y3; s2 = __builtin_elementwise_fma(d, d, s2);
                float e2 = s2.x + s2.y + 1e-12f;
                KB[t >> 1][t & 1] = __builtin_amdgcn_exp2f(
                    fmaf(__builtin_amdgcn_sqrtf(e2), CSCALE, CBIAS));
            }
        };
        build(KA0, KB0, P0);
        build(KA1, KB1, P0 + 1);

        float pp0 = 0.0f, pp1 = 0.0f, E0 = 1.0f, E1 = 1.0f;
        float w0c = 1.0f, w0p = 1.0f, w1c = 1.0f, w1p = 1.0f;
        swv0[lane] = 1.0f;
        swv1[lane] = 1.0f;

        const int blens[9] = {4, 12, 12, 12, 12, 12, 12, 12, 12};  // 100 T-steps
        #pragma unroll 1
        for (int blk = 0; blk < 9; ++blk) {
            int L = blens[blk];
            #pragma unroll 1
            for (int s = 0; s < L; ++s) {
                const float4* wp0 = (const float4*)(&swv0[h * 32 + q * 16]);
                const float4* wp1 = (const float4*)(&swv1[h * 32 + q * 16]);
                float4 A0 = wp0[0], A1 = wp0[1], A2 = wp0[2], A3 = wp0[3];
                float4 B0 = wp1[0], B1 = wp1[1], B2 = wp1[2], B3 = wp1[3];
                // ---- chain 0 dot ----
                f2 aA0 = KA0[0] * f2{A0.x, A0.y};
                f2 aA1 = KA0[1] * f2{A0.z, A0.w};
                f2 aB0 = KB0[0] * f2{A0.x, A0.y};
                f2 aB1 = KB0[1] * f2{A0.z, A0.w};
                aA0 = __builtin_elementwise_fma(KA0[2], f2{A1.x, A1.y}, aA0);
                aA1 = __builtin_elementwise_fma(KA0[3], f2{A1.z, A1.w}, aA1);
                aB0 = __builtin_elementwise_fma(KB0[2], f2{A1.x, A1.y}, aB0);
                aB1 = __builtin_elementwise_fma(KB0[3], f2{A1.z, A1.w}, aB1);
                aA0 = __builtin_elementwise_fma(KA0[4], f2{A2.x, A2.y}, aA0);
                aA1 = __builtin_elementwise_fma(KA0[5], f2{A2.z, A2.w}, aA1);
                aB0 = __builtin_elementwise_fma(KB0[4], f2{A2.x, A2.y}, aB0);
                aB1 = __builtin_elementwise_fma(KB0[5], f2{A2.z, A2.w}, aB1);
                aA0 = __builtin_elementwise_fma(KA0[6], f2{A3.x, A3.y}, aA0);
                aA1 = __builtin_elementwise_fma(KA0[7], f2{A3.z, A3.w}, aA1);
                aB0 = __builtin_elementwise_fma(KB0[6], f2{A3.x, A3.y}, aB0);
                aB1 = __builtin_elementwise_fma(KB0[7], f2{A3.z, A3.w}, aB1);
                f2 aa0 = aA0 + aA1;
                f2 bb0 = aB0 + aB1;
                float pa0 = aa0.x + aa0.y;
                float pb0 = bb0.x + bb0.y;
                // ---- chain 1 dot ----
                f2 cA0 = KA1[0] * f2{B0.x, B0.y};
                f2 cA1 = KA1[1] * f2{B0.z, B0.w};
                f2 cB0 = KB1[0] * f2{B0.x, B0.y};
                f2 cB1 = KB1[1] * f2{B0.z, B0.w};
                cA0 = __builtin_elementwise_fma(KA1[2], f2{B1.x, B1.y}, cA0);
                cA1 = __builtin_elementwise_fma(KA1[3], f2{B1.z, B1.w}, cA1);
                cB0 = __builtin_elementwise_fma(KB1[2], f2{B1.x, B1.y}, cB0);
                cB1 = __builtin_elementwise_fma(KB1[3], f2{B1.z, B1.w}, cB1);
                cA0 = __builtin_elementwise_fma(KA1[4], f2{B2.x, B2.y}, cA0);
                cA1 = __builtin_elementwise_fma(KA1[5], f2{B2.z, B2.w}, cA1);
                cB0 = __builtin_elementwise_fma(KB1[4], f2{B2.x, B2.y}, cB0);
                cB1 = __builtin_elementwise_fma(KB1[5], f2{B2.z, B2.w}, cB1);
                cA0 = __builtin_elementwise_fma(KA1[6], f2{B3.x, B3.y}, cA0);
                cA1 = __builtin_elementwise_fma(KA1[7], f2{B3.z, B3.w}, cA1);
                cB0 = __builtin_elementwise_fma(KB1[6], f2{B3.x, B3.y}, cB0);
                cB1 = __builtin_elementwise_fma(KB1[7], f2{B3.z, B3.w}, cB1);
                f2 aa1 = cA0 + cA1;
                f2 bb1 = cB0 + cB1;
                float pa1 = aa1.x + aa1.y;
                float pb1 = bb1.x + bb1.y;
                // combine + update, both chains
                float o0 = __shfl_xor(pb0, 16);
                float o1 = __shfl_xor(pb1, 16);
                w0p = w0c;
                w0c = __builtin_amdgcn_rcpf(pa0 + o0) * E0;
                w1p = w1c;
                w1c = __builtin_amdgcn_rcpf(pa1 + o1) * E1;
                swv0[h * 32 + i] = w0c;
                swv1[h * 32 + i] = w1c;
            }
            if (blk < 8) {
                float d0 = __builtin_amdgcn_logf(w0c);
                float d1 = __builtin_amdgcn_logf(w1c);
                pp0 += d0;
                pp1 += d1;
                spv0[h * 32 + i] = d0;
                spv1[h * 32 + i] = d1;
                {
                    const float4* dv = (const float4*)(&spv0[h * 32 + q * 16]);
                    float4 D0 = dv[0], D1 = dv[1], D2 = dv[2], D3 = dv[3];
                    float ex[16];
                    ex[0]  = __builtin_amdgcn_exp2f(D0.x);
                    ex[1]  = __builtin_amdgcn_exp2f(D0.y);
                    ex[2]  = __builtin_amdgcn_exp2f(D0.z);
                    ex[3]  = __builtin_amdgcn_exp2f(D0.w);
                    ex[4]  = __builtin_amdgcn_exp2f(D1.x);
                    ex[5]  = __builtin_amdgcn_exp2f(D1.y);
                    ex[6]  = __builtin_amdgcn_exp2f(D1.z);
                    ex[7]  = __builtin_amdgcn_exp2f(D1.w);
                    ex[8]  = __builtin_amdgcn_exp2f(D2.x);
                    ex[9]  = __builtin_amdgcn_exp2f(D2.y);
                    ex[10] = __builtin_amdgcn_exp2f(D2.z);
                    ex[11] = __builtin_amdgcn_exp2f(D2.w);
                    ex[12] = __builtin_amdgcn_exp2f(D3.x);
                    ex[13] = __builtin_amdgcn_exp2f(D3.y);
                    ex[14] = __builtin_amdgcn_exp2f(D3.z);
                    ex[15] = __builtin_amdgcn_exp2f(D3.w);
                    #pragma unroll
                    for (int t2 = 0; t2 < 8; ++t2) {
                        f2 ee = f2{ex[2 * t2], ex[2 * t2 + 1]};
                        KA0[t2] *= ee;
                        KB0[t2] *= ee;
                    }
                }
                {
                    const float4* dv = (const float4*)(&spv1[h * 32 + q * 16]);
                    float4 D0 = dv[0], D1 = dv[1], D2 = dv[2], D3 = dv[3];
                    float ex[16];
                    ex[0]  = __builtin_amdgcn_exp2f(D0.x);
                    ex[1]  = __builtin_amdgcn_exp2f(D0.y);
                    ex[2]  = __builtin_amdgcn_exp2f(D0.z);
                    ex[3]  = __builtin_amdgcn_exp2f(D0.w);
                    ex[4]  = __builtin_amdgcn_exp2f(D1.x);
                    ex[5]  = __builtin_amdgcn_exp2f(D1.y);
                    ex[6]  = __builtin_amdgcn_exp2f(D1.z);
                    ex[7]  = __builtin_amdgcn_exp2f(D1.w);
                    ex[8]  = __builtin_amdgcn_exp2f(D2.x);
                    ex[9]  = __builtin_amdgcn_exp2f(D2.y);
                    ex[10] = __builtin_amdgcn_exp2f(D2.z);
                    ex[11] = __builtin_amdgcn_exp2f(D2.w);
                    ex[12] = __builtin_amdgcn_exp2f(D3.x);
                    ex[13] = __builtin_amdgcn_exp2f(D3.y);
                    ex[14] = __builtin_amdgcn_exp2f(D3.z);
                    ex[15] = __builtin_amdgcn_exp2f(D3.w);
                    #pragma unroll
                    for (int t2 = 0; t2 < 8; ++t2) {
                        f2 ee = f2{ex[2 * t2], ex[2 * t2 + 1]};
                        KA1[t2] *= ee;
                        KB1[t2] *= ee;
                    }
                }
                E0 = __builtin_amdgcn_exp2f(-pp0);
                E1 = __builtin_amdgcn_exp2f(-pp1);
                w0c = 1.0f;
                w1c = 1.0f;
                swv0[lane] = 1.0f;
                swv1[lane] = 1.0f;
            }
        }

        // z99 = pp + log2(wprev), z100 = pp + log2(wcur); cost = eps*ln2*sum/32
        float zs0 = 2.0f * pp0 + __builtin_amdgcn_logf(w0p)
                  + __builtin_amdgcn_logf(w0c);
        float zs1 = 2.0f * pp1 + __builtin_amdgcn_logf(w1p)
                  + __builtin_amdgcn_logf(w1c);
        #pragma unroll
        for (int off = 16; off > 0; off >>= 1) {
            zs0 += __shfl_xor(zs0, off);
            zs1 += __shfl_xor(zs1, off);
        }
        if (i == 0) {
            unsafeAtomicAdd(&dist[P0],     -0.5f * (zs0 * (EPS_F * LN2_F / 32.0f)));
            unsafeAtomicAdd(&dist[P0 + 1], -0.5f * (zs1 * (EPS_F * LN2_F / 32.0f)));
        }
    } else {
        // ===== off-diagonal: 16 lanes/pair, 2 rows/lane, 4 pairs/wave =====
        int g = lane >> 4, r = lane & 15;
        int p = (blockIdx.x - 2048) * 8 + w * 4 + g;   // 1024*8 = 8192 pairs

        float* base = S + g * 640;
        float* sX = base;
        float* sY = base + 256;
        float* sf = base + 512;
        float* sg = base + 544;
        float* su = base + 576;
        float* sv = base + 608;

        {
            const float4* zx = (const float4*)(Z + (size_t)p * 256);
            const float4* zy = (const float4*)(Z + (size_t)(N_PAIRS + p) * 256);
            float4* x4 = (float4*)sX;
            float4* y4 = (float4*)sY;
            #pragma unroll
            for (int c = 0; c < 4; ++c) {
                x4[c * 16 + r] = zx[c * 16 + r];
                y4[c * 16 + r] = zy[c * 16 + r];
            }
        }
        *(f2*)(&sg[2 * r]) = f2{0.0f, 0.0f};

        int i0 = 2 * r, i1 = 2 * r + 1;
        // Lane owns C rows i0,i1 (CrowA/B) and C cols i0,i1 (CcolA/B).
        // After Phase A these are transformed IN PLACE into KR/KC.
        f2 CrowA[16], CrowB[16], CcolA[16], CcolB[16];
        {
            const f2* xa = (const f2*)(&sX[i0 * 8]);
            f2 a0 = xa[0], a1 = xa[1], a2 = xa[2], a3 = xa[3];
            const f2* xb = (const f2*)(&sX[i1 * 8]);
            f2 b0 = xb[0], b1 = xb[1], b2 = xb[2], b3 = xb[3];
            const f2* ya = (const f2*)(&sY[i0 * 8]);
            f2 c0 = ya[0], c1 = ya[1], c2 = ya[2], c3 = ya[3];
            const f2* yb = (const f2*)(&sY[i1 * 8]);
            f2 e0 = yb[0], e1 = yb[1], e2 = yb[2], e3 = yb[3];
            #pragma unroll
            for (int t = 0; t < 32; ++t) {
                const f2* yt = (const f2*)(&sY[t * 8]);
                f2 y0 = yt[0], y1 = yt[1], y2 = yt[2], y3 = yt[3];
                f2 d, s2;
                d = a0 - y0; s2 = d * d;
                d = a1 - y1; s2 = __builtin_elementwise_fma(d, d, s2);
                d = a2 - y2; s2 = __builtin_elementwise_fma(d, d, s2);
                d = a3 - y3; s2 = __builtin_elementwise_fma(d, d, s2);
                float dA = s2.x + s2.y + 1e-12f;
                CrowA[t >> 1][t & 1] = fmaf(__builtin_amdgcn_sqrtf(dA), CSCALE, CBIAS);
                d = b0 - y0; s2 = d * d;
                d = b1 - y1; s2 = __builtin_elementwise_fma(d, d, s2);
                d = b2 - y2; s2 = __builtin_elementwise_fma(d, d, s2);
                d = b3 - y3; s2 = __builtin_elementwise_fma(d, d, s2);
                float dB = s2.x + s2.y + 1e-12f;
                CrowB[t >> 1][t & 1] = fmaf(__builtin_amdgcn_sqrtf(dB), CSCALE, CBIAS);
                const f2* xt = (const f2*)(&sX[t * 8]);
                f2 q0 = xt[0], q1 = xt[1], q2 = xt[2], q3 = xt[3];
                d = q0 - c0; s2 = d * d;
                d = q1 - c1; s2 = __builtin_elementwise_fma(d, d, s2);
                d = q2 - c2; s2 = __builtin_elementwise_fma(d, d, s2);
                d = q3 - c3; s2 = __builtin_elementwise_fma(d, d, s2);
                float dC = s2.x + s2.y + 1e-12f;
                CcolA[t >> 1][t & 1] = fmaf(__builtin_amdgcn_sqrtf(dC), CSCALE, CBIAS);
                d = q0 - e0; s2 = d * d;
                d = q1 - e1; s2 = __builtin_elementwise_fma(d, d, s2);
                d = q2 - e2; s2 = __builtin_elementwise_fma(d, d, s2);
                d = q3 - e3; s2 = __builtin_elementwise_fma(d, d, s2);
                float dD = s2.x + s2.y + 1e-12f;
                CcolB[t >> 1][t & 1] = fmaf(__builtin_amdgcn_sqrtf(dD), CSCALE, CBIAS);
            }
        }

        float ft0 = 0.0f, ft1 = 0.0f, gt0 = 0.0f, gt1 = 0.0f;

        // Phase A: 2 log-domain iterations (per-row 32-wide LSE, no shfl)
        #pragma unroll 1
        for (int it = 0; it < 2; ++it) {
            {
                const float4* gp = (const float4*)sg;
                float4 G[8];
                #pragma unroll
                for (int r8 = 0; r8 < 8; ++r8) G[r8] = gp[r8];
                // row i0
                {
                    f2 val[16], m2 = f2{-1e30f, -1e30f};
                    #pragma unroll
                    for (int r8 = 0; r8 < 8; ++r8) {
                        val[2 * r8]     = f2{G[r8].x, G[r8].y} + CrowA[2 * r8];
                        val[2 * r8 + 1] = f2{G[r8].z, G[r8].w} + CrowA[2 * r8 + 1];
                        m2 = __builtin_elementwise_max(m2, val[2 * r8]);
                        m2 = __builtin_elementwise_max(m2, val[2 * r8 + 1]);
                    }
                    float m = fmaxf(m2.x, m2.y);
                    f2 mm = f2{m, m};
                    float s0 = 0.0f, s1 = 0.0f;
                    #pragma unroll
                    for (int t2 = 0; t2 < 16; ++t2) {
                        f2 e = val[t2] - mm;
                        s0 += __builtin_amdgcn_exp2f(e.x);
                        s1 += __builtin_amdgcn_exp2f(e.y);
                    }
                    ft0 = -(m + __builtin_amdgcn_logf(s0 + s1));
                }
                // row i1
                {
                    f2 val[16], m2 = f2{-1e30f, -1e30f};
                    #pragma unroll
                    for (int r8 = 0; r8 < 8; ++r8) {
                        val[2 * r8]     = f2{G[r8].x, G[r8].y} + CrowB[2 * r8];
                        val[2 * r8 + 1] = f2{G[r8].z, G[r8].w} + CrowB[2 * r8 + 1];
                        m2 = __builtin_elementwise_max(m2, val[2 * r8]);
                        m2 = __builtin_elementwise_max(m2, val[2 * r8 + 1]);
                    }
                    float m = fmaxf(m2.x, m2.y);
                    f2 mm = f2{m, m};
                    float s0 = 0.0f, s1 = 0.0f;
                    #pragma unroll
                    for (int t2 = 0; t2 < 16; ++t2) {
                        f2 e = val[t2] - mm;
                        s0 += __builtin_amdgcn_exp2f(e.x);
                        s1 += __builtin_amdgcn_exp2f(e.y);
                    }
                    ft1 = -(m + __builtin_amdgcn_logf(s0 + s1));
                }
            }
            *(f2*)(&sf[2 * r]) = f2{ft0, ft1};
            {
                const float4* fp = (const float4*)sf;
                float4 F[8];
                #pragma unroll
                for (int r8 = 0; r8 < 8; ++r8) F[r8] = fp[r8];
                // col i0
                {
                    f2 val[16], m2 = f2{-1e30f, -1e30f};
                    #pragma unroll
                    for (int r8 = 0; r8 < 8; ++r8) {
                        val[2 * r8]     = f2{F[r8].x, F[r8].y} + CcolA[2 * r8];
                        val[2 * r8 + 1] = f2{F[r8].z, F[r8].w} + CcolA[2 * r8 + 1];
                        m2 = __builtin_elementwise_max(m2, val[2 * r8]);
                        m2 = __builtin_elementwise_max(m2, val[2 * r8 + 1]);
                    }
                    float m = fmaxf(m2.x, m2.y);
                    f2 mm = f2{m, m};
                    float s0 = 0.0f, s1 = 0.0f;
                    #pragma unroll
                    for (int t2 = 0; t2 < 16; ++t2) {
                        f2 e = val[t2] - mm;
                        s0 += __builtin_amdgcn_exp2f(e.x);
                        s1 += __builtin_amdgcn_exp2f(e.y);
                    }
                    gt0 = -(m + __builtin_amdgcn_logf(s0 + s1));
                }
                // col i1
                {
                    f2 val[16], m2 = f2{-1e30f, -1e30f};
                    #pragma unroll
                    for (int r8 = 0; r8 < 8; ++r8) {
                        val[2 * r8]     = f2{F[r8].x, F[r8].y} + CcolB[2 * r8];
                        val[2 * r8 + 1] = f2{F[r8].z, F[r8].w} + CcolB[2 * r8 + 1];
                        m2 = __builtin_elementwise_max(m2, val[2 * r8]);
                        m2 = __builtin_elementwise_max(m2, val[2 * r8 + 1]);
                    }
                    float m = fmaxf(m2.x, m2.y);
                    f2 mm = f2{m, m};
                    float s0 = 0.0f, s1 = 0.0f;
                    #pragma unroll
                    for (int t2 = 0; t2 < 16; ++t2) {
                        f2 e = val[t2] - mm;
                        s0 += __builtin_amdgcn_exp2f(e.x);
                        s1 += __builtin_amdgcn_exp2f(e.y);
                    }
                    gt1 = -(m + __builtin_amdgcn_logf(s0 + s1));
                }
            }
            *(f2*)(&sg[2 * r]) = f2{gt0, gt1};
        }

        // Transform C -> K in place (Crow* become KR rows, Ccol* become KC rows)
        {
            const float4* gp = (const float4*)sg;
            #pragma unroll
            for (int r8 = 0; r8 < 8; ++r8) {
                float4 G = gp[r8];
                f2 t0, t1;
                t0 = CrowA[2 * r8]     + f2{G.x, G.y} + f2{ft0, ft0};
                t1 = CrowA[2 * r8 + 1] + f2{G.z, G.w} + f2{ft0, ft0};
                CrowA[2 * r8].x     = __builtin_amdgcn_exp2f(t0.x);
                CrowA[2 * r8].y     = __builtin_amdgcn_exp2f(t0.y);
                CrowA[2 * r8 + 1].x = __builtin_amdgcn_exp2f(t1.x);
                CrowA[2 * r8 + 1].y = __builtin_amdgcn_exp2f(t1.y);
                t0 = CrowB[2 * r8]     + f2{G.x, G.y} + f2{ft1, ft1};
                t1 = CrowB[2 * r8 + 1] + f2{G.z, G.w} + f2{ft1, ft1};
                CrowB[2 * r8].x     = __builtin_amdgcn_exp2f(t0.x);
                CrowB[2 * r8].y     = __builtin_amdgcn_exp2f(t0.y);
                CrowB[2 * r8 + 1].x = __builtin_amdgcn_exp2f(t1.x);
                CrowB[2 * r8 + 1].y = __builtin_amdgcn_exp2f(t1.y);
            }
            const float4* fp = (const float4*)sf;
            #pragma unroll
            for (int r8 = 0; r8 < 8; ++r8) {
                float4 F = fp[r8];
                f2 t0, t1;
                t0 = CcolA[2 * r8]     + f2{F.x, F.y} + f2{gt0, gt0};
                t1 = CcolA[2 * r8 + 1] + f2{F.z, F.w} + f2{gt0, gt0};
                CcolA[2 * r8].x     = __builtin_amdgcn_exp2f(t0.x);
                CcolA[2 * r8].y     = __builtin_amdgcn_exp2f(t0.y);
                CcolA[2 * r8 + 1].x = __builtin_amdgcn_exp2f(t1.x);
                CcolA[2 * r8 + 1].y = __builtin_amdgcn_exp2f(t1.y);
                t0 = CcolB[2 * r8]     + f2{F.x, F.y} + f2{gt1, gt1};
                t1 = CcolB[2 * r8 + 1] + f2{F.z, F.w} + f2{gt1, gt1};
                CcolB[2 * r8].x     = __builtin_amdgcn_exp2f(t0.x);
                CcolB[2 * r8].y     = __builtin_amdgcn_exp2f(t0.y);
                CcolB[2 * r8 + 1].x = __builtin_amdgcn_exp2f(t1.x);
                CcolB[2 * r8 + 1].y = __builtin_amdgcn_exp2f(t1.y);
            }
        }
        *(f2*)(&sv[2 * r]) = f2{1.0f, 1.0f};
        float u0 = 1.0f, u1 = 1.0f, v0 = 1.0f, v1 = 1.0f;

        const int blens[5] = {6, 6, 12, 12, 12};   // 48 exp iters total
        #pragma unroll 1
        for (int blk = 0; blk < 5; ++blk) {
            int L = blens[blk];
            #pragma unroll 2
            for (int s6 = 0; s6 < L; ++s6) {
                // f-step: u_i = 1/(KR_i . v) for i0,i1 — one v read, two dots
                {
                    const float4* vp = (const float4*)sv;
                    f2 aA0, aA1, aB0, aB1;
                    float4 A = vp[0];
                    aA0 = CrowA[0] * f2{A.x, A.y};
                    aA1 = CrowA[1] * f2{A.z, A.w};
                    aB0 = CrowB[0] * f2{A.x, A.y};
                    aB1 = CrowB[1] * f2{A.z, A.w};
                    #pragma unroll
                    for (int rr = 1; rr < 8; ++rr) {
                        float4 B = vp[rr];
                        aA0 = __builtin_elementwise_fma(CrowA[2 * rr],     f2{B.x, B.y}, aA0);
                        aA1 = __builtin_elementwise_fma(CrowA[2 * rr + 1], f2{B.z, B.w}, aA1);
                        aB0 = __builtin_elementwise_fma(CrowB[2 * rr],     f2{B.x, B.y}, aB0);
                        aB1 = __builtin_elementwise_fma(CrowB[2 * rr + 1], f2{B.z, B.w}, aB1);
                    }
                    f2 sa = aA0 + aA1;
                    f2 sb = aB0 + aB1;
                    u0 = __builtin_amdgcn_rcpf(sa.x + sa.y);
                    u1 = __builtin_amdgcn_rcpf(sb.x + sb.y);
                }
                *(f2*)(&su[2 * r]) = f2{u0, u1};
                // g-step: v_i = 1/(KC_i . u)
                {
                    const float4* up = (const float4*)su;
                    f2 aA0, aA1, aB0, aB1;
                    float4 A = up[0];
                    aA0 = CcolA[0] * f2{A.x, A.y};
                    aA1 = CcolA[1] * f2{A.z, A.w};
                    aB0 = CcolB[0] * f2{A.x, A.y};
                    aB1 = CcolB[1] * f2{A.z, A.w};
                    #pragma unroll
                    for (int rr = 1; rr < 8; ++rr) {
                        float4 B = up[rr];
                        aA0 = __builtin_elementwise_fma(CcolA[2 * rr],     f2{B.x, B.y}, aA0);
                        aA1 = __builtin_elementwise_fma(CcolA[2 * rr + 1], f2{B.z, B.w}, aA1);
                        aB0 = __builtin_elementwise_fma(CcolB[2 * rr],     f2{B.x, B.y}, aB0);
                        aB1 = __builtin_elementwise_fma(CcolB[2 * rr + 1], f2{B.z, B.w}, aB1);
                    }
                    f2 sa = aA0 + aA1;
                    f2 sb = aB0 + aB1;
                    v0 = __builtin_amdgcn_rcpf(sa.x + sa.y);
                    v1 = __builtin_amdgcn_rcpf(sb.x + sb.y);
                }
                *(f2*)(&sv[2 * r]) = f2{v0, v1};
            }
            if (blk < 4) {
                float df0 = __builtin_amdgcn_logf(u0);
                float df1 = __builtin_amdgcn_logf(u1);
                float dg0 = __builtin_amdgcn_logf(v0);
                float dg1 = __builtin_amdgcn_logf(v1);
                ft0 += df0; ft1 += df1; gt0 += dg0; gt1 += dg1;
                *(f2*)(&sf[2 * r]) = f2{df0, df1};
                *(f2*)(&sg[2 * r]) = f2{dg0, dg1};
                // KR_i[j] *= exp2(df_i + dg_j); KC_i[j] *= exp2(dg_i + df_j)
                const float4* dgv = (const float4*)sg;
                #pragma unroll
                for (int r8 = 0; r8 < 8; ++r8) {
                    float4 D = dgv[r8];
                    f2 eA0, eA1, eB0, eB1;
                    eA0.x = __builtin_amdgcn_exp2f(df0 + D.x);
                    eA0.y = __builtin_amdgcn_exp2f(df0 + D.y);
                    eA1.x = __builtin_amdgcn_exp2f(df0 + D.z);
                    eA1.y = __builtin_amdgcn_exp2f(df0 + D.w);
                    eB0.x = __builtin_amdgcn_exp2f(df1 + D.x);
                    eB0.y = __builtin_amdgcn_exp2f(df1 + D.y);
                    eB1.x = __builtin_amdgcn_exp2f(df1 + D.z);
                    eB1.y = __builtin_amdgcn_exp2f(df1 + D.w);
                    CrowA[2 * r8]     *= eA0;
                    CrowA[2 * r8 + 1] *= eA1;
                    CrowB[2 * r8]     *= eB0;
                    CrowB[2 * r8 + 1] *= eB1;
                }
                const float4* dfv = (const float4*)sf;
                #pragma unroll
                for (int r8 = 0; r8 < 8; ++r8) {
                    float4 D = dfv[r8];
                    f2 eA0, eA1, eB0, eB1;
                    eA0.x = __builtin_amdgcn_exp2f(dg0 + D.x);
                    eA0.y = __builtin_amdgcn_exp2f(dg0 + D.y);
                    eA1.x = __builtin_amdgcn_exp2f(dg0 + D.z);
                    eA1.y = __builtin_amdgcn_exp2f(dg0 + D.w);
                    eB0.x = __builtin_amdgcn_exp2f(dg1 + D.x);
                    eB0.y = __builtin_amdgcn_exp2f(dg1 + D.y);
                    eB1.x = __builtin_amdgcn_exp2f(dg1 + D.z);
                    eB1.y = __builtin_amdgcn_exp2f(dg1 + D.w);
                    CcolA[2 * r8]     *= eA0;
                    CcolA[2 * r8 + 1] *= eA1;
                    CcolB[2 * r8]     *= eB0;
                    CcolB[2 * r8 + 1] *= eB1;
                }
                *(f2*)(&sv[2 * r]) = f2{1.0f, 1.0f};
                u0 = 1.0f; u1 = 1.0f; v0 = 1.0f; v1 = 1.0f;
            }
        }
        ft0 += __builtin_amdgcn_logf(u0);
        ft1 += __builtin_amdgcn_logf(u1);
        gt0 += __builtin_amdgcn_logf(v0);
        gt1 += __builtin_amdgcn_logf(v1);

        // OT = eps*ln2*(sum f + sum g)/32; reduce within 16-lane group
        float vs = (ft0 + ft1) + (gt0 + gt1);
        #pragma unroll
        for (int off = 8; off > 0; off >>= 1) vs += __shfl_xor(vs, off);
        if (r == 0) {
            float cost = vs * (EPS_F * LN2_F / 32.0f);
            unsafeAtomicAdd(&dist[p], cost);
        }
    }
}

// ------------------------------------------------------------------ finalize
__global__ void k_finalize(const float* __restrict__ dist,
                           const float* __restrict__ gd, float* __restrict__ out) {
    __shared__ float red[256];
    float s = 0.0f;
    for (int i = threadIdx.x; i < N_PAIRS; i += 256) {
        float g = gd[i];
        s += fabsf(dist[i] - g) / g;
    }
    red[threadIdx.x] = s;
    __syncthreads();
    for (int o = 128; o > 0; o >>= 1) {
        if (threadIdx.x < o) red[threadIdx.x] += red[threadIdx.x + o];
        __syncthreads();
    }
    if (threadIdx.x == 0) out[0] = red[0] * (1.0f / N_PAIRS);
}

// -------------------------------------------------------------------- launch
extern "C" void kernel_launch(void* const* d_in, const int* in_sizes, int n_in,
                              void* d_out, int out_size, void* d_ws, size_t ws_size,
                              hipStream_t stream) {
    const float* x    = (const float*)d_in[0];   // [50000,128]
    const float* W    = (const float*)d_in[1];   // [128,256]
    const int*   eidx = (const int*)d_in[2];     // [2,800000]
    const int*   pair = (const int*)d_in[3];     // [2,8192] flat = 16384 slots
    const float* gd   = (const float*)d_in[4];   // [8192]

    char* ws = (char*)d_ws;
    size_t off = 0;
    int*   cnt    = (int*)  (ws + off); off += (size_t)N_NODES * 4;
    int*   flags  = (int*)  (ws + off); off += (size_t)N_NODES * 4;
    float* dist   = (float*)(ws + off); off += (size_t)N_PAIRS * 4;
    size_t zero_bytes = off;                     // cnt+flags+dist contiguous
    int*   bucket = (int*)  (ws + off); off += (size_t)N_NODES * CAP * 4; // 12.8 MB
    float* Z      = (float*)(ws + off); off += (size_t)N_SLOTS * 256 * 4; // 16.8 MB

    hipMemsetAsync(d_ws, 0, zero_bytes, stream);
    k_mark    <<<(N_SLOTS + 255) / 256, 256, 0, stream>>>(pair, flags);
    k_scatter <<<N_EDGES / 256, 256, 0, stream>>>(eidx, flags, cnt, bucket);
    k_gemm    <<<N_SLOTS / 16, 256, 0, stream>>>(pair, x, cnt, bucket, W, Z);
    k_sinkhorn<<<3072, 128, 0, stream>>>(Z, dist);
    k_finalize<<<1, 256, 0, stream>>>(dist, gd, (float*)d_out);
}

// Round 8
// 237.522 us; speedup vs baseline: 1.3991x; 1.0508x over previous
//
#include <hip/hip_runtime.h>

#define N_NODES 50000
#define N_EDGES 800000
#define N_PAIRS 8192
#define N_SLOTS (2 * N_PAIRS)
#define CAP     64          // per-node bucket capacity; P(deg>63)~5e-19

// Sinkhorn constants (log2 domain):
//   C2 = -(C/eps + ln32)*log2e ; potentials kept in /(eps*ln2) units
#define INV_EPS   20.0f
#define LOG2E_F   1.4426950408889634f
#define LN2_F     0.6931471805599453f
#define LN32_F    3.4657359027997265f
#define EPS_F     0.05f

typedef float f2 __attribute__((ext_vector_type(2)));

// ---------------------------------------------------------------- mark needed
__global__ void k_mark(const int* __restrict__ pairs, int* __restrict__ flags) {
    int t = blockIdx.x * 256 + threadIdx.x;
    if (t < N_SLOTS) flags[pairs[t]] = 1;
}

// ---------------------------------------- scatter into fixed-cap buckets
__global__ __launch_bounds__(256) void k_scatter(
        const int* __restrict__ eidx, const int* __restrict__ flags,
        int* __restrict__ cnt, int* __restrict__ bucket) {
    int t = blockIdx.x * 256 + threadIdx.x;   // exact grid: 800000/256
    int dst = eidx[N_EDGES + t];
    if (!flags[dst]) return;
    int pos = atomicAdd(&cnt[dst], 1);
    if (pos < CAP) bucket[dst * CAP + pos] = eidx[t];
}

// ------------------------------------ fused gather + GEMM + relu
__global__ __launch_bounds__(256) void k_gemm(
        const int* __restrict__ pairs, const float* __restrict__ x,
        const int* __restrict__ cnt, const int* __restrict__ bucket,
        const float* __restrict__ W, float* __restrict__ Z) {
    __shared__ __align__(16) float Us[16 * 128];
    int sbase = blockIdx.x * 16;
    int t = threadIdx.x;
    int wave = t >> 6, lane = t & 63;

    #pragma unroll
    for (int rr = 0; rr < 4; ++rr) {
        int r = wave * 4 + rr;
        int node = pairs[sbase + r];
        int n = cnt[node];
        int m = (n < CAP) ? n : CAP;
        const int* bk = bucket + node * CAP;
        float ax = 0.0f, ay = 0.0f;
        int k = 0;
        for (; k + 4 <= m; k += 4) {
            int s0 = bk[k], s1 = bk[k + 1], s2 = bk[k + 2], s3 = bk[k + 3];
            float2 v0 = *(const float2*)(x + (size_t)s0 * 128 + lane * 2);
            float2 v1 = *(const float2*)(x + (size_t)s1 * 128 + lane * 2);
            float2 v2 = *(const float2*)(x + (size_t)s2 * 128 + lane * 2);
            float2 v3 = *(const float2*)(x + (size_t)s3 * 128 + lane * 2);
            ax += (v0.x + v1.x) + (v2.x + v3.x);
            ay += (v0.y + v1.y) + (v2.y + v3.y);
        }
        for (; k < m; ++k) {
            int s0 = bk[k];
            float2 v0 = *(const float2*)(x + (size_t)s0 * 128 + lane * 2);
            ax += v0.x;
            ay += v0.y;
        }
        float rdeg = 1.0f / fmaxf((float)n, 1.0f);
        float2 xv = *(const float2*)(x + (size_t)node * 128 + lane * 2);
        float2 o;
        o.x = fmaf(ax, rdeg, xv.x);
        o.y = fmaf(ay, rdeg, xv.y);
        *(float2*)(Us + r * 128 + lane * 2) = o;
    }
    __syncthreads();

    int jq = t & 63;   // column quad: cols 4*jq..4*jq+3
    int rq = t >> 6;   // row quad group: rows 4*rq..4*rq+3
    float acc[4][4] = {};
    const float4* Wv = (const float4*)W;   // W[128][256]

    for (int k4 = 0; k4 < 32; ++k4) {
        float4 wv[4];
        #pragma unroll
        for (int i = 0; i < 4; ++i) wv[i] = Wv[(size_t)(k4 * 4 + i) * 64 + jq];
        #pragma unroll
        for (int r = 0; r < 4; ++r) {
            float4 uv = *(const float4*)(Us + (rq * 4 + r) * 128 + k4 * 4);
            float uk0 = uv.x, uk1 = uv.y, uk2 = uv.z, uk3 = uv.w;
            acc[r][0] = fmaf(uk0, wv[0].x, acc[r][0]);
            acc[r][1] = fmaf(uk0, wv[0].y, acc[r][1]);
            acc[r][2] = fmaf(uk0, wv[0].z, acc[r][2]);
            acc[r][3] = fmaf(uk0, wv[0].w, acc[r][3]);
            acc[r][0] = fmaf(uk1, wv[1].x, acc[r][0]);
            acc[r][1] = fmaf(uk1, wv[1].y, acc[r][1]);
            acc[r][2] = fmaf(uk1, wv[1].z, acc[r][2]);
            acc[r][3] = fmaf(uk1, wv[1].w, acc[r][3]);
            acc[r][0] = fmaf(uk2, wv[2].x, acc[r][0]);
            acc[r][1] = fmaf(uk2, wv[2].y, acc[r][1]);
            acc[r][2] = fmaf(uk2, wv[2].z, acc[r][2]);
            acc[r][3] = fmaf(uk2, wv[2].w, acc[r][3]);
            acc[r][0] = fmaf(uk3, wv[3].x, acc[r][0]);
            acc[r][1] = fmaf(uk3, wv[3].y, acc[r][1]);
            acc[r][2] = fmaf(uk3, wv[3].z, acc[r][2]);
            acc[r][3] = fmaf(uk3, wv[3].w, acc[r][3]);
        }
    }

    #pragma unroll
    for (int r = 0; r < 4; ++r) {
        float4 o;
        o.x = fmaxf(acc[r][0], 0.0f);
        o.y = fmaxf(acc[r][1], 0.0f);
        o.z = fmaxf(acc[r][2], 0.0f);
        o.w = fmaxf(acc[r][3], 0.0f);
        *(float4*)(Z + (size_t)(sbase + rq * 4 + r) * 256 + jq * 4) = o;
    }
}

// ------------------------------------------------------------------- sinkhorn
// 128-thread blocks (2 waves), no __syncthreads anywhere.
//  blocks [0,2048):    diagonal — one wave per TWO pairs (dual-chain ILP).
//  blocks [2048,4096): off-diagonal — HALF-WAVE per pair (2 pairs/wave).
__global__ __launch_bounds__(128) void k_sinkhorn(
        const float* __restrict__ Z, float* __restrict__ dist) {
    __shared__ __align__(16) float smem[2][1280];   // 10240 B

    int w = threadIdx.x >> 6;
    int lane = threadIdx.x & 63;
    float* S = &smem[w][0];
    const float CSCALE = -INV_EPS * LOG2E_F;
    const float CBIAS  = -LN32_F * LOG2E_F;

    if (blockIdx.x < 2048) {
        // ==== diagonal path: 2 pairs/wave, dual independent chains ====
        int h = lane >> 5, i = lane & 31;
        int q = (i >> 4) & 1;                 // k-half this lane reads
        int ip = i ^ 16;                      // partner row
        int P0 = blockIdx.x * 4 + w * 2;      // 2048*2*2 = 8192 pairs

        float* sP   = S;                      // 512 floats, transient per build
        float* swv0 = S + 512;
        float* spv0 = S + 576;
        float* swv1 = S + 640;
        float* spv1 = S + 704;

        f2 KA0[8], KB0[8], KA1[8], KB1[8];

        auto build = [&](f2 (&KA)[8], f2 (&KB)[8], int P) {
            int src = h ? (N_PAIRS + P) : P;
            float* sPh = sP + h * 256;
            {
                const float4* zp = (const float4*)(Z + (size_t)src * 256);
                *(float4*)(&sPh[i * 8])     = zp[i * 2];
                *(float4*)(&sPh[i * 8 + 4]) = zp[i * 2 + 1];
            }
            const f2* xp = (const f2*)(&sPh[i * 8]);
            f2 x0 = xp[0], x1 = xp[1], x2 = xp[2], x3 = xp[3];
            const f2* bp = (const f2*)(&sPh[ip * 8]);
            f2 b0 = bp[0], b1 = bp[1], b2 = bp[2], b3 = bp[3];
            #pragma unroll
            for (int t = 0; t < 16; ++t) {
                int j = q * 16 + t;
                const f2* yp = (const f2*)(&sPh[j * 8]);
                f2 y0 = yp[0], y1 = yp[1], y2 = yp[2], y3 = yp[3];
                f2 d, s2;
                d = x0 - y0; s2 = d * d;
                d = x1 - y1; s2 = __builtin_elementwise_fma(d, d, s2);
                d = x2 - y2; s2 = __builtin_elementwise_fma(d, d, s2);
                d = x3 - y3; s2 = __builtin_elementwise_fma(d, d, s2);
                float d2 = s2.x + s2.y + 1e-12f;
                KA[t >> 1][t & 1] = __builtin_amdgcn_exp2f(
                    fmaf(__builtin_amdgcn_sqrtf(d2), CSCALE, CBIAS));
                d = b0 - y0; s2 = d * d;
                d = b1 - y1; s2 = __builtin_elementwise_fma(d, d, s2);
                d = b2 - y2; s2 = __builtin_elementwise_fma(d, d, s2);
                d = b3 - y3; s2 = __builtin_elementwise_fma(d, d, s2);
                float e2 = s2.x + s2.y + 1e-12f;
                KB[t >> 1][t & 1] = __builtin_amdgcn_exp2f(
                    fmaf(__builtin_amdgcn_sqrtf(e2), CSCALE, CBIAS));
            }
        };
        build(KA0, KB0, P0);
        build(KA1, KB1, P0 + 1);

        float pp0 = 0.0f, pp1 = 0.0f, E0 = 1.0f, E1 = 1.0f;
        float w0c = 1.0f, w0p = 1.0f, w1c = 1.0f, w1p = 1.0f;
        swv0[lane] = 1.0f;
        swv1[lane] = 1.0f;

        const int blens[9] = {4, 12, 12, 12, 12, 12, 12, 12, 12};  // 100 T-steps
        #pragma unroll 1
        for (int blk = 0; blk < 9; ++blk) {
            int L = blens[blk];
            #pragma unroll 1
            for (int s = 0; s < L; ++s) {
                const float4* wp0 = (const float4*)(&swv0[h * 32 + q * 16]);
                const float4* wp1 = (const float4*)(&swv1[h * 32 + q * 16]);
                float4 A0 = wp0[0], A1 = wp0[1], A2 = wp0[2], A3 = wp0[3];
                float4 B0 = wp1[0], B1 = wp1[1], B2 = wp1[2], B3 = wp1[3];
                // ---- chain 0 dot ----
                f2 aA0 = KA0[0] * f2{A0.x, A0.y};
                f2 aA1 = KA0[1] * f2{A0.z, A0.w};
                f2 aB0 = KB0[0] * f2{A0.x, A0.y};
                f2 aB1 = KB0[1] * f2{A0.z, A0.w};
                aA0 = __builtin_elementwise_fma(KA0[2], f2{A1.x, A1.y}, aA0);
                aA1 = __builtin_elementwise_fma(KA0[3], f2{A1.z, A1.w}, aA1);
                aB0 = __builtin_elementwise_fma(KB0[2], f2{A1.x, A1.y}, aB0);
                aB1 = __builtin_elementwise_fma(KB0[3], f2{A1.z, A1.w}, aB1);
                aA0 = __builtin_elementwise_fma(KA0[4], f2{A2.x, A2.y}, aA0);
                aA1 = __builtin_elementwise_fma(KA0[5], f2{A2.z, A2.w}, aA1);
                aB0 = __builtin_elementwise_fma(KB0[4], f2{A2.x, A2.y}, aB0);
                aB1 = __builtin_elementwise_fma(KB0[5], f2{A2.z, A2.w}, aB1);
                aA0 = __builtin_elementwise_fma(KA0[6], f2{A3.x, A3.y}, aA0);
                aA1 = __builtin_elementwise_fma(KA0[7], f2{A3.z, A3.w}, aA1);
                aB0 = __builtin_elementwise_fma(KB0[6], f2{A3.x, A3.y}, aB0);
                aB1 = __builtin_elementwise_fma(KB0[7], f2{A3.z, A3.w}, aB1);
                f2 aa0 = aA0 + aA1;
                f2 bb0 = aB0 + aB1;
                float pa0 = aa0.x + aa0.y;
                float pb0 = bb0.x + bb0.y;
                // ---- chain 1 dot ----
                f2 cA0 = KA1[0] * f2{B0.x, B0.y};
                f2 cA1 = KA1[1] * f2{B0.z, B0.w};
                f2 cB0 = KB1[0] * f2{B0.x, B0.y};
                f2 cB1 = KB1[1] * f2{B0.z, B0.w};
                cA0 = __builtin_elementwise_fma(KA1[2], f2{B1.x, B1.y}, cA0);
                cA1 = __builtin_elementwise_fma(KA1[3], f2{B1.z, B1.w}, cA1);
                cB0 = __builtin_elementwise_fma(KB1[2], f2{B1.x, B1.y}, cB0);
                cB1 = __builtin_elementwise_fma(KB1[3], f2{B1.z, B1.w}, cB1);
                cA0 = __builtin_elementwise_fma(KA1[4], f2{B2.x, B2.y}, cA0);
                cA1 = __builtin_elementwise_fma(KA1[5], f2{B2.z, B2.w}, cA1);
                cB0 = __builtin_elementwise_fma(KB1[4], f2{B2.x, B2.y}, cB0);
                cB1 = __builtin_elementwise_fma(KB1[5], f2{B2.z, B2.w}, cB1);
                cA0 = __builtin_elementwise_fma(KA1[6], f2{B3.x, B3.y}, cA0);
                cA1 = __builtin_elementwise_fma(KA1[7], f2{B3.z, B3.w}, cA1);
                cB0 = __builtin_elementwise_fma(KB1[6], f2{B3.x, B3.y}, cB0);
                cB1 = __builtin_elementwise_fma(KB1[7], f2{B3.z, B3.w}, cB1);
                f2 aa1 = cA0 + cA1;
                f2 bb1 = cB0 + cB1;
                float pa1 = aa1.x + aa1.y;
                float pb1 = bb1.x + bb1.y;
                // combine + update, both chains
                float o0 = __shfl_xor(pb0, 16);
                float o1 = __shfl_xor(pb1, 16);
                w0p = w0c;
                w0c = __builtin_amdgcn_rcpf(pa0 + o0) * E0;
                w1p = w1c;
                w1c = __builtin_amdgcn_rcpf(pa1 + o1) * E1;
                swv0[h * 32 + i] = w0c;
                swv1[h * 32 + i] = w1c;
            }
            if (blk < 8) {
                float d0 = __builtin_amdgcn_logf(w0c);
                float d1 = __builtin_amdgcn_logf(w1c);
                pp0 += d0;
                pp1 += d1;
                spv0[h * 32 + i] = d0;
                spv1[h * 32 + i] = d1;
                {
                    const float4* dv = (const float4*)(&spv0[h * 32 + q * 16]);
                    float4 D0 = dv[0], D1 = dv[1], D2 = dv[2], D3 = dv[3];
                    float ex[16];
                    ex[0]  = __builtin_amdgcn_exp2f(D0.x);
                    ex[1]  = __builtin_amdgcn_exp2f(D0.y);
                    ex[2]  = __builtin_amdgcn_exp2f(D0.z);
                    ex[3]  = __builtin_amdgcn_exp2f(D0.w);
                    ex[4]  = __builtin_amdgcn_exp2f(D1.x);
                    ex[5]  = __builtin_amdgcn_exp2f(D1.y);
                    ex[6]  = __builtin_amdgcn_exp2f(D1.z);
                    ex[7]  = __builtin_amdgcn_exp2f(D1.w);
                    ex[8]  = __builtin_amdgcn_exp2f(D2.x);
                    ex[9]  = __builtin_amdgcn_exp2f(D2.y);
                    ex[10] = __builtin_amdgcn_exp2f(D2.z);
                    ex[11] = __builtin_amdgcn_exp2f(D2.w);
                    ex[12] = __builtin_amdgcn_exp2f(D3.x);
                    ex[13] = __builtin_amdgcn_exp2f(D3.y);
                    ex[14] = __builtin_amdgcn_exp2f(D3.z);
                    ex[15] = __builtin_amdgcn_exp2f(D3.w);
                    #pragma unroll
                    for (int t2 = 0; t2 < 8; ++t2) {
                        f2 ee = f2{ex[2 * t2], ex[2 * t2 + 1]};
                        KA0[t2] *= ee;
                        KB0[t2] *= ee;
                    }
                }
                {
                    const float4* dv = (const float4*)(&spv1[h * 32 + q * 16]);
                    float4 D0 = dv[0], D1 = dv[1], D2 = dv[2], D3 = dv[3];
                    float ex[16];
                    ex[0]  = __builtin_amdgcn_exp2f(D0.x);
                    ex[1]  = __builtin_amdgcn_exp2f(D0.y);
                    ex[2]  = __builtin_amdgcn_exp2f(D0.z);
                    ex[3]  = __builtin_amdgcn_exp2f(D0.w);
                    ex[4]  = __builtin_amdgcn_exp2f(D1.x);
                    ex[5]  = __builtin_amdgcn_exp2f(D1.y);
                    ex[6]  = __builtin_amdgcn_exp2f(D1.z);
                    ex[7]  = __builtin_amdgcn_exp2f(D1.w);
                    ex[8]  = __builtin_amdgcn_exp2f(D2.x);
                    ex[9]  = __builtin_amdgcn_exp2f(D2.y);
                    ex[10] = __builtin_amdgcn_exp2f(D2.z);
                    ex[11] = __builtin_amdgcn_exp2f(D2.w);
                    ex[12] = __builtin_amdgcn_exp2f(D3.x);
                    ex[13] = __builtin_amdgcn_exp2f(D3.y);
                    ex[14] = __builtin_amdgcn_exp2f(D3.z);
                    ex[15] = __builtin_amdgcn_exp2f(D3.w);
                    #pragma unroll
                    for (int t2 = 0; t2 < 8; ++t2) {
                        f2 ee = f2{ex[2 * t2], ex[2 * t2 + 1]};
                        KA1[t2] *= ee;
                        KB1[t2] *= ee;
                    }
                }
                E0 = __builtin_amdgcn_exp2f(-pp0);
                E1 = __builtin_amdgcn_exp2f(-pp1);
                w0c = 1.0f;
                w1c = 1.0f;
                swv0[lane] = 1.0f;
                swv1[lane] = 1.0f;
            }
        }

        // z99 = pp + log2(wprev), z100 = pp + log2(wcur); cost = eps*ln2*sum/32
        float zs0 = 2.0f * pp0 + __builtin_amdgcn_logf(w0p)
                  + __builtin_amdgcn_logf(w0c);
        float zs1 = 2.0f * pp1 + __builtin_amdgcn_logf(w1p)
                  + __builtin_amdgcn_logf(w1c);
        #pragma unroll
        for (int off = 16; off > 0; off >>= 1) {
            zs0 += __shfl_xor(zs0, off);
            zs1 += __shfl_xor(zs1, off);
        }
        if (i == 0) {
            unsafeAtomicAdd(&dist[P0],     -0.5f * (zs0 * (EPS_F * LN2_F / 32.0f)));
            unsafeAtomicAdd(&dist[P0 + 1], -0.5f * (zs1 * (EPS_F * LN2_F / 32.0f)));
        }
    } else {
        // ============ off-diagonal path: half-wave per pair ============
        int h = lane >> 5, l = lane & 31;
        int p = (blockIdx.x - 2048) * 4 + w * 2 + h;   // 2048*4 = 8192 pairs

        float* base = S + h * 640;
        float* sX = base;
        float* sY = base + 256;
        float* sf = base + 512;
        float* sg = base + 544;
        float* su = base + 576;
        float* sv = base + 608;

        {
            const float4* zx = (const float4*)(Z + (size_t)p * 256);
            const float4* zy = (const float4*)(Z + (size_t)(N_PAIRS + p) * 256);
            *(float4*)(&sX[l * 8])     = zx[l * 2];
            *(float4*)(&sX[l * 8 + 4]) = zx[l * 2 + 1];
            *(float4*)(&sY[l * 8])     = zy[l * 2];
            *(float4*)(&sY[l * 8 + 4]) = zy[l * 2 + 1];
        }
        sg[l] = 0.0f;

        // Crow[j] = C2[l][j]; Ccol[i] = C2[i][l]
        f2 Crow[16], Ccol[16];
        {
            const f2* xp = (const f2*)(&sX[l * 8]);
            f2 x0 = xp[0], x1 = xp[1], x2 = xp[2], x3 = xp[3];
            const f2* yp = (const f2*)(&sY[l * 8]);
            f2 y0 = yp[0], y1 = yp[1], y2 = yp[2], y3 = yp[3];
            #pragma unroll
            for (int t = 0; t < 32; ++t) {
                const f2* op = (const f2*)(&sY[t * 8]);
                f2 d, s2;
                d = x0 - op[0]; s2 = d * d;
                d = x1 - op[1]; s2 = __builtin_elementwise_fma(d, d, s2);
                d = x2 - op[2]; s2 = __builtin_elementwise_fma(d, d, s2);
                d = x3 - op[3]; s2 = __builtin_elementwise_fma(d, d, s2);
                float d2 = s2.x + s2.y + 1e-12f;
                Crow[t >> 1][t & 1] = fmaf(__builtin_amdgcn_sqrtf(d2), CSCALE, CBIAS);
                const f2* qp = (const f2*)(&sX[t * 8]);
                d = qp[0] - y0; s2 = d * d;
                d = qp[1] - y1; s2 = __builtin_elementwise_fma(d, d, s2);
                d = qp[2] - y2; s2 = __builtin_elementwise_fma(d, d, s2);
                d = qp[3] - y3; s2 = __builtin_elementwise_fma(d, d, s2);
                float e2 = s2.x + s2.y + 1e-12f;
                Ccol[t >> 1][t & 1] = fmaf(__builtin_amdgcn_sqrtf(e2), CSCALE, CBIAS);
            }
        }

        float ft = 0.0f, gt = 0.0f;

        // Phase A: 2 log-domain iterations (full 32-wide LSE per lane, no shfl)
        #pragma unroll 1
        for (int it = 0; it < 2; ++it) {
            {
                const float4* gp = (const float4*)sg;
                float4 G[8];
                #pragma unroll
                for (int r = 0; r < 8; ++r) G[r] = gp[r];
                f2 val[16], m2 = f2{-1e30f, -1e30f};
                #pragma unroll
                for (int r = 0; r < 8; ++r) {
                    val[2 * r]     = f2{G[r].x, G[r].y} + Crow[2 * r];
                    val[2 * r + 1] = f2{G[r].z, G[r].w} + Crow[2 * r + 1];
                    m2 = __builtin_elementwise_max(m2, val[2 * r]);
                    m2 = __builtin_elementwise_max(m2, val[2 * r + 1]);
                }
                float m = fmaxf(m2.x, m2.y);
                f2 mm = f2{m, m};
                float s0 = 0.0f, s1 = 0.0f;
                #pragma unroll
                for (int t2 = 0; t2 < 16; ++t2) {
                    f2 e = val[t2] - mm;
                    s0 += __builtin_amdgcn_exp2f(e.x);
                    s1 += __builtin_amdgcn_exp2f(e.y);
                }
                ft = -(m + __builtin_amdgcn_logf(s0 + s1));
            }
            sf[l] = ft;
            {
                const float4* fp = (const float4*)sf;
                float4 F[8];
                #pragma unroll
                for (int r = 0; r < 8; ++r) F[r] = fp[r];
                f2 val[16], m2 = f2{-1e30f, -1e30f};
                #pragma unroll
                for (int r = 0; r < 8; ++r) {
                    val[2 * r]     = f2{F[r].x, F[r].y} + Ccol[2 * r];
                    val[2 * r + 1] = f2{F[r].z, F[r].w} + Ccol[2 * r + 1];
                    m2 = __builtin_elementwise_max(m2, val[2 * r]);
                    m2 = __builtin_elementwise_max(m2, val[2 * r + 1]);
                }
                float m = fmaxf(m2.x, m2.y);
                f2 mm = f2{m, m};
                float s0 = 0.0f, s1 = 0.0f;
                #pragma unroll
                for (int t2 = 0; t2 < 16; ++t2) {
                    f2 e = val[t2] - mm;
                    s0 += __builtin_amdgcn_exp2f(e.x);
                    s1 += __builtin_amdgcn_exp2f(e.y);
                }
                gt = -(m + __builtin_amdgcn_logf(s0 + s1));
            }
            sg[l] = gt;
        }

        // Build K (row copy + col copy); C dies here.
        f2 KR[16], KC[16];
        {
            const float4* gp = (const float4*)sg;
            #pragma unroll
            for (int r = 0; r < 8; ++r) {
                float4 G = gp[r];
                f2 a0 = f2{G.x, G.y} + Crow[2 * r] + f2{ft, ft};
                f2 a1 = f2{G.z, G.w} + Crow[2 * r + 1] + f2{ft, ft};
                KR[2 * r].x     = __builtin_amdgcn_exp2f(a0.x);
                KR[2 * r].y     = __builtin_amdgcn_exp2f(a0.y);
                KR[2 * r + 1].x = __builtin_amdgcn_exp2f(a1.x);
                KR[2 * r + 1].y = __builtin_amdgcn_exp2f(a1.y);
            }
            const float4* fp = (const float4*)sf;
            #pragma unroll
            for (int r = 0; r < 8; ++r) {
                float4 F = fp[r];
                f2 a0 = f2{F.x, F.y} + Ccol[2 * r] + f2{gt, gt};
                f2 a1 = f2{F.z, F.w} + Ccol[2 * r + 1] + f2{gt, gt};
                KC[2 * r].x     = __builtin_amdgcn_exp2f(a0.x);
                KC[2 * r].y     = __builtin_amdgcn_exp2f(a0.y);
                KC[2 * r + 1].x = __builtin_amdgcn_exp2f(a1.x);
                KC[2 * r + 1].y = __builtin_amdgcn_exp2f(a1.y);
            }
        }
        sv[l] = 1.0f;
        float ureg = 1.0f, vreg = 1.0f;

        const int blens[5] = {6, 6, 12, 12, 12};   // 48 exp iters total
        #pragma unroll 1
        for (int blk = 0; blk < 5; ++blk) {
            int L = blens[blk];
            #pragma unroll 2
            for (int s6 = 0; s6 < L; ++s6) {
                // f-step: u_l = 1/(KR . v), full dot, no shfl
                {
                    const float4* vp = (const float4*)sv;
                    f2 acc0, acc1;
                    float4 A = vp[0];
                    acc0 = KR[0] * f2{A.x, A.y};
                    acc1 = KR[1] * f2{A.z, A.w};
                    #pragma unroll
                    for (int r = 1; r < 8; ++r) {
                        float4 B = vp[r];
                        acc0 = __builtin_elementwise_fma(KR[2 * r],     f2{B.x, B.y}, acc0);
                        acc1 = __builtin_elementwise_fma(KR[2 * r + 1], f2{B.z, B.w}, acc1);
                    }
                    f2 a = acc0 + acc1;
                    ureg = __builtin_amdgcn_rcpf(a.x + a.y);
                }
                su[l] = ureg;
                // g-step: v_l = 1/(KC . u)
                {
                    const float4* up = (const float4*)su;
                    f2 acc0, acc1;
                    float4 A = up[0];
                    acc0 = KC[0] * f2{A.x, A.y};
                    acc1 = KC[1] * f2{A.z, A.w};
                    #pragma unroll
                    for (int r = 1; r < 8; ++r) {
                        float4 B = up[r];
                        acc0 = __builtin_elementwise_fma(KC[2 * r],     f2{B.x, B.y}, acc0);
                        acc1 = __builtin_elementwise_fma(KC[2 * r + 1], f2{B.z, B.w}, acc1);
                    }
                    f2 a = acc0 + acc1;
                    vreg = __builtin_amdgcn_rcpf(a.x + a.y);
                }
                sv[l] = vreg;
            }
            if (blk < 4) {
                float df = __builtin_amdgcn_logf(ureg);
                float dg = __builtin_amdgcn_logf(vreg);
                ft += df;
                gt += dg;
                sf[l] = df;
                sg[l] = dg;
                // KR[j] *= exp2(df + dg_j); KC[i] *= exp2(dg + df_i)
                const float4* dgv = (const float4*)sg;
                #pragma unroll
                for (int r = 0; r < 8; ++r) {
                    float4 D = dgv[r];
                    f2 e0, e1;
                    e0.x = __builtin_amdgcn_exp2f(df + D.x);
                    e0.y = __builtin_amdgcn_exp2f(df + D.y);
                    e1.x = __builtin_amdgcn_exp2f(df + D.z);
                    e1.y = __builtin_amdgcn_exp2f(df + D.w);
                    KR[2 * r]     *= e0;
                    KR[2 * r + 1] *= e1;
                }
                const float4* dfv = (const float4*)sf;
                #pragma unroll
                for (int r = 0; r < 8; ++r) {
                    float4 D = dfv[r];
                    f2 e0, e1;
                    e0.x = __builtin_amdgcn_exp2f(dg + D.x);
                    e0.y = __builtin_amdgcn_exp2f(dg + D.y);
                    e1.x = __builtin_amdgcn_exp2f(dg + D.z);
                    e1.y = __builtin_amdgcn_exp2f(dg + D.w);
                    KC[2 * r]     *= e0;
                    KC[2 * r + 1] *= e1;
                }
                sv[l] = 1.0f;
                ureg = 1.0f;
                vreg = 1.0f;
            }
        }
        ft += __builtin_amdgcn_logf(ureg);
        gt += __builtin_amdgcn_logf(vreg);

        // OT = eps*ln2*(sum_l f_l + g_l)/32; reduce within half-wave
        float v = ft + gt;
        #pragma unroll
        for (int off = 16; off > 0; off >>= 1) v += __shfl_xor(v, off);
        if (l == 0) {
            float cost = v * (EPS_F * LN2_F / 32.0f);
            unsafeAtomicAdd(&dist[p], cost);
        }
    }
}

// ------------------------------------------------------------------ finalize
__global__ __launch_bounds__(1024) void k_finalize(
        const float* __restrict__ dist,
        const float* __restrict__ gd, float* __restrict__ out) {
    __shared__ float red[1024];
    float s = 0.0f;
    for (int i = threadIdx.x; i < N_PAIRS; i += 1024) {
        float g = gd[i];
        s += fabsf(dist[i] - g) / g;
    }
    red[threadIdx.x] = s;
    __syncthreads();
    for (int o = 512; o > 0; o >>= 1) {
        if (threadIdx.x < o) red[threadIdx.x] += red[threadIdx.x + o];
        __syncthreads();
    }
    if (threadIdx.x == 0) out[0] = red[0] * (1.0f / N_PAIRS);
}

// -------------------------------------------------------------------- launch
extern "C" void kernel_launch(void* const* d_in, const int* in_sizes, int n_in,
                              void* d_out, int out_size, void* d_ws, size_t ws_size,
                              hipStream_t stream) {
    const float* x    = (const float*)d_in[0];   // [50000,128]
    const float* W    = (const float*)d_in[1];   // [128,256]
    const int*   eidx = (const int*)d_in[2];     // [2,800000]
    const int*   pair = (const int*)d_in[3];     // [2,8192] flat = 16384 slots
    const float* gd   = (const float*)d_in[4];   // [8192]

    char* ws = (char*)d_ws;
    size_t off = 0;
    int*   cnt    = (int*)  (ws + off); off += (size_t)N_NODES * 4;
    int*   flags  = (int*)  (ws + off); off += (size_t)N_NODES * 4;
    float* dist   = (float*)(ws + off); off += (size_t)N_PAIRS * 4;
    size_t zero_bytes = off;                     // cnt+flags+dist contiguous
    int*   bucket = (int*)  (ws + off); off += (size_t)N_NODES * CAP * 4; // 12.8 MB
    float* Z      = (float*)(ws + off); off += (size_t)N_SLOTS * 256 * 4; // 16.8 MB

    hipMemsetAsync(d_ws, 0, zero_bytes, stream);
    k_mark    <<<(N_SLOTS + 255) / 256, 256, 0, stream>>>(pair, flags);
    k_scatter <<<N_EDGES / 256, 256, 0, stream>>>(eidx, flags, cnt, bucket);
    k_gemm    <<<N_SLOTS / 16, 256, 0, stream>>>(pair, x, cnt, bucket, W, Z);
    k_sinkhorn<<<4096, 128, 0, stream>>>(Z, dist);
    k_finalize<<<1, 1024, 0, stream>>>(dist, gd, (float*)d_out);
}

// Round 9
// 237.266 us; speedup vs baseline: 1.4006x; 1.0011x over previous
//
#include <hip/hip_runtime.h>

#define N_NODES 50000
#define N_EDGES 800000
#define N_PAIRS 8192
#define N_SLOTS (2 * N_PAIRS)
#define CAP     64          // per-node bucket capacity; P(deg>63)~5e-19

// Sinkhorn constants (log2 domain):
//   C2 = -(C/eps + ln32)*log2e ; potentials kept in /(eps*ln2) units
#define INV_EPS   20.0f
#define LOG2E_F   1.4426950408889634f
#define LN2_F     0.6931471805599453f
#define LN32_F    3.4657359027997265f
#define EPS_F     0.05f

typedef float f2 __attribute__((ext_vector_type(2)));

// ---------------------------------------------------------------- mark needed
__global__ void k_mark(const int* __restrict__ pairs, int* __restrict__ flags) {
    int t = blockIdx.x * 256 + threadIdx.x;
    if (t < N_SLOTS) flags[pairs[t]] = 1;
}

// ---------------------------------------- scatter into fixed-cap buckets
__global__ __launch_bounds__(256) void k_scatter(
        const int* __restrict__ eidx, const int* __restrict__ flags,
        int* __restrict__ cnt, int* __restrict__ bucket) {
    int t = blockIdx.x * 256 + threadIdx.x;   // exact grid: 800000/256
    int dst = eidx[N_EDGES + t];
    if (!flags[dst]) return;
    int pos = atomicAdd(&cnt[dst], 1);
    if (pos < CAP) bucket[dst * CAP + pos] = eidx[t];
}

// ------------------------------------ fused gather + GEMM + relu
// Gather loop 8-wide: 8 independent 512B row-loads in flight per iteration
// (gather is L3-latency-bound; MLP is the lever).
__global__ __launch_bounds__(256) void k_gemm(
        const int* __restrict__ pairs, const float* __restrict__ x,
        const int* __restrict__ cnt, const int* __restrict__ bucket,
        const float* __restrict__ W, float* __restrict__ Z) {
    __shared__ __align__(16) float Us[16 * 128];
    int sbase = blockIdx.x * 16;
    int t = threadIdx.x;
    int wave = t >> 6, lane = t & 63;

    #pragma unroll
    for (int rr = 0; rr < 4; ++rr) {
        int r = wave * 4 + rr;
        int node = pairs[sbase + r];
        int n = cnt[node];
        int m = (n < CAP) ? n : CAP;
        const int* bk = bucket + node * CAP;
        float ax = 0.0f, ay = 0.0f;
        int k = 0;
        for (; k + 8 <= m; k += 8) {
            int s0 = bk[k],     s1 = bk[k + 1], s2 = bk[k + 2], s3 = bk[k + 3];
            int s4 = bk[k + 4], s5 = bk[k + 5], s6 = bk[k + 6], s7 = bk[k + 7];
            float2 v0 = *(const float2*)(x + (size_t)s0 * 128 + lane * 2);
            float2 v1 = *(const float2*)(x + (size_t)s1 * 128 + lane * 2);
            float2 v2 = *(const float2*)(x + (size_t)s2 * 128 + lane * 2);
            float2 v3 = *(const float2*)(x + (size_t)s3 * 128 + lane * 2);
            float2 v4 = *(const float2*)(x + (size_t)s4 * 128 + lane * 2);
            float2 v5 = *(const float2*)(x + (size_t)s5 * 128 + lane * 2);
            float2 v6 = *(const float2*)(x + (size_t)s6 * 128 + lane * 2);
            float2 v7 = *(const float2*)(x + (size_t)s7 * 128 + lane * 2);
            ax += ((v0.x + v1.x) + (v2.x + v3.x)) + ((v4.x + v5.x) + (v6.x + v7.x));
            ay += ((v0.y + v1.y) + (v2.y + v3.y)) + ((v4.y + v5.y) + (v6.y + v7.y));
        }
        for (; k + 4 <= m; k += 4) {
            int s0 = bk[k], s1 = bk[k + 1], s2 = bk[k + 2], s3 = bk[k + 3];
            float2 v0 = *(const float2*)(x + (size_t)s0 * 128 + lane * 2);
            float2 v1 = *(const float2*)(x + (size_t)s1 * 128 + lane * 2);
            float2 v2 = *(const float2*)(x + (size_t)s2 * 128 + lane * 2);
            float2 v3 = *(const float2*)(x + (size_t)s3 * 128 + lane * 2);
            ax += (v0.x + v1.x) + (v2.x + v3.x);
            ay += (v0.y + v1.y) + (v2.y + v3.y);
        }
        for (; k < m; ++k) {
            int s0 = bk[k];
            float2 v0 = *(const float2*)(x + (size_t)s0 * 128 + lane * 2);
            ax += v0.x;
            ay += v0.y;
        }
        float rdeg = 1.0f / fmaxf((float)n, 1.0f);
        float2 xv = *(const float2*)(x + (size_t)node * 128 + lane * 2);
        float2 o;
        o.x = fmaf(ax, rdeg, xv.x);
        o.y = fmaf(ay, rdeg, xv.y);
        *(float2*)(Us + r * 128 + lane * 2) = o;
    }
    __syncthreads();

    int jq = t & 63;   // column quad: cols 4*jq..4*jq+3
    int rq = t >> 6;   // row quad group: rows 4*rq..4*rq+3
    float acc[4][4] = {};
    const float4* Wv = (const float4*)W;   // W[128][256]

    for (int k4 = 0; k4 < 32; ++k4) {
        float4 wv[4];
        #pragma unroll
        for (int i = 0; i < 4; ++i) wv[i] = Wv[(size_t)(k4 * 4 + i) * 64 + jq];
        #pragma unroll
        for (int r = 0; r < 4; ++r) {
            float4 uv = *(const float4*)(Us + (rq * 4 + r) * 128 + k4 * 4);
            float uk0 = uv.x, uk1 = uv.y, uk2 = uv.z, uk3 = uv.w;
            acc[r][0] = fmaf(uk0, wv[0].x, acc[r][0]);
            acc[r][1] = fmaf(uk0, wv[0].y, acc[r][1]);
            acc[r][2] = fmaf(uk0, wv[0].z, acc[r][2]);
            acc[r][3] = fmaf(uk0, wv[0].w, acc[r][3]);
            acc[r][0] = fmaf(uk1, wv[1].x, acc[r][0]);
            acc[r][1] = fmaf(uk1, wv[1].y, acc[r][1]);
            acc[r][2] = fmaf(uk1, wv[1].z, acc[r][2]);
            acc[r][3] = fmaf(uk1, wv[1].w, acc[r][3]);
            acc[r][0] = fmaf(uk2, wv[2].x, acc[r][0]);
            acc[r][1] = fmaf(uk2, wv[2].y, acc[r][1]);
            acc[r][2] = fmaf(uk2, wv[2].z, acc[r][2]);
            acc[r][3] = fmaf(uk2, wv[2].w, acc[r][3]);
            acc[r][0] = fmaf(uk3, wv[3].x, acc[r][0]);
            acc[r][1] = fmaf(uk3, wv[3].y, acc[r][1]);
            acc[r][2] = fmaf(uk3, wv[3].z, acc[r][2]);
            acc[r][3] = fmaf(uk3, wv[3].w, acc[r][3]);
        }
    }

    #pragma unroll
    for (int r = 0; r < 4; ++r) {
        float4 o;
        o.x = fmaxf(acc[r][0], 0.0f);
        o.y = fmaxf(acc[r][1], 0.0f);
        o.z = fmaxf(acc[r][2], 0.0f);
        o.w = fmaxf(acc[r][3], 0.0f);
        *(float4*)(Z + (size_t)(sbase + rq * 4 + r) * 256 + jq * 4) = o;
    }
}

// ------------------------------------------------------------------- sinkhorn
// 128-thread blocks (2 waves), no __syncthreads anywhere.
//  blocks [0,2048):    diagonal — one wave per TWO pairs (dual-chain ILP).
//  blocks [2048,4096): off-diagonal — HALF-WAVE per pair (2 pairs/wave).
__global__ __launch_bounds__(128) void k_sinkhorn(
        const float* __restrict__ Z, float* __restrict__ dist) {
    __shared__ __align__(16) float smem[2][1280];   // 10240 B

    int w = threadIdx.x >> 6;
    int lane = threadIdx.x & 63;
    float* S = &smem[w][0];
    const float CSCALE = -INV_EPS * LOG2E_F;
    const float CBIAS  = -LN32_F * LOG2E_F;

    if (blockIdx.x < 2048) {
        // ==== diagonal path: 2 pairs/wave, dual independent chains ====
        int h = lane >> 5, i = lane & 31;
        int q = (i >> 4) & 1;                 // k-half this lane reads
        int ip = i ^ 16;                      // partner row
        int P0 = blockIdx.x * 4 + w * 2;      // 2048*2*2 = 8192 pairs

        float* sP   = S;                      // 512 floats, transient per build
        float* swv0 = S + 512;
        float* spv0 = S + 576;
        float* swv1 = S + 640;
        float* spv1 = S + 704;

        f2 KA0[8], KB0[8], KA1[8], KB1[8];

        auto build = [&](f2 (&KA)[8], f2 (&KB)[8], int P) {
            int src = h ? (N_PAIRS + P) : P;
            float* sPh = sP + h * 256;
            {
                const float4* zp = (const float4*)(Z + (size_t)src * 256);
                *(float4*)(&sPh[i * 8])     = zp[i * 2];
                *(float4*)(&sPh[i * 8 + 4]) = zp[i * 2 + 1];
            }
            const f2* xp = (const f2*)(&sPh[i * 8]);
            f2 x0 = xp[0], x1 = xp[1], x2 = xp[2], x3 = xp[3];
            const f2* bp = (const f2*)(&sPh[ip * 8]);
            f2 b0 = bp[0], b1 = bp[1], b2 = bp[2], b3 = bp[3];
            #pragma unroll
            for (int t = 0; t < 16; ++t) {
                int j = q * 16 + t;
                const f2* yp = (const f2*)(&sPh[j * 8]);
                f2 y0 = yp[0], y1 = yp[1], y2 = yp[2], y3 = yp[3];
                f2 d, s2;
                d = x0 - y0; s2 = d * d;
                d = x1 - y1; s2 = __builtin_elementwise_fma(d, d, s2);
                d = x2 - y2; s2 = __builtin_elementwise_fma(d, d, s2);
                d = x3 - y3; s2 = __builtin_elementwise_fma(d, d, s2);
                float d2 = s2.x + s2.y + 1e-12f;
                KA[t >> 1][t & 1] = __builtin_amdgcn_exp2f(
                    fmaf(__builtin_amdgcn_sqrtf(d2), CSCALE, CBIAS));
                d = b0 - y0; s2 = d * d;
                d = b1 - y1; s2 = __builtin_elementwise_fma(d, d, s2);
                d = b2 - y2; s2 = __builtin_elementwise_fma(d, d, s2);
                d = b3 - y3; s2 = __builtin_elementwise_fma(d, d, s2);
                float e2 = s2.x + s2.y + 1e-12f;
                KB[t >> 1][t & 1] = __builtin_amdgcn_exp2f(
                    fmaf(__builtin_amdgcn_sqrtf(e2), CSCALE, CBIAS));
            }
        };
        build(KA0, KB0, P0);
        build(KA1, KB1, P0 + 1);

        float pp0 = 0.0f, pp1 = 0.0f, E0 = 1.0f, E1 = 1.0f;
        float w0c = 1.0f, w0p = 1.0f, w1c = 1.0f, w1p = 1.0f;
        swv0[lane] = 1.0f;
        swv1[lane] = 1.0f;

        const int blens[9] = {4, 12, 12, 12, 12, 12, 12, 12, 12};  // 100 T-steps
        #pragma unroll 1
        for (int blk = 0; blk < 9; ++blk) {
            int L = blens[blk];
            #pragma unroll 1
            for (int s = 0; s < L; ++s) {
                const float4* wp0 = (const float4*)(&swv0[h * 32 + q * 16]);
                const float4* wp1 = (const float4*)(&swv1[h * 32 + q * 16]);
                float4 A0 = wp0[0], A1 = wp0[1], A2 = wp0[2], A3 = wp0[3];
                float4 B0 = wp1[0], B1 = wp1[1], B2 = wp1[2], B3 = wp1[3];
                // ---- chain 0 dot ----
                f2 aA0 = KA0[0] * f2{A0.x, A0.y};
                f2 aA1 = KA0[1] * f2{A0.z, A0.w};
                f2 aB0 = KB0[0] * f2{A0.x, A0.y};
                f2 aB1 = KB0[1] * f2{A0.z, A0.w};
                aA0 = __builtin_elementwise_fma(KA0[2], f2{A1.x, A1.y}, aA0);
                aA1 = __builtin_elementwise_fma(KA0[3], f2{A1.z, A1.w}, aA1);
                aB0 = __builtin_elementwise_fma(KB0[2], f2{A1.x, A1.y}, aB0);
                aB1 = __builtin_elementwise_fma(KB0[3], f2{A1.z, A1.w}, aB1);
                aA0 = __builtin_elementwise_fma(KA0[4], f2{A2.x, A2.y}, aA0);
                aA1 = __builtin_elementwise_fma(KA0[5], f2{A2.z, A2.w}, aA1);
                aB0 = __builtin_elementwise_fma(KB0[4], f2{A2.x, A2.y}, aB0);
                aB1 = __builtin_elementwise_fma(KB0[5], f2{A2.z, A2.w}, aB1);
                aA0 = __builtin_elementwise_fma(KA0[6], f2{A3.x, A3.y}, aA0);
                aA1 = __builtin_elementwise_fma(KA0[7], f2{A3.z, A3.w}, aA1);
                aB0 = __builtin_elementwise_fma(KB0[6], f2{A3.x, A3.y}, aB0);
                aB1 = __builtin_elementwise_fma(KB0[7], f2{A3.z, A3.w}, aB1);
                f2 aa0 = aA0 + aA1;
                f2 bb0 = aB0 + aB1;
                float pa0 = aa0.x + aa0.y;
                float pb0 = bb0.x + bb0.y;
                // ---- chain 1 dot ----
                f2 cA0 = KA1[0] * f2{B0.x, B0.y};
                f2 cA1 = KA1[1] * f2{B0.z, B0.w};
                f2 cB0 = KB1[0] * f2{B0.x, B0.y};
                f2 cB1 = KB1[1] * f2{B0.z, B0.w};
                cA0 = __builtin_elementwise_fma(KA1[2], f2{B1.x, B1.y}, cA0);
                cA1 = __builtin_elementwise_fma(KA1[3], f2{B1.z, B1.w}, cA1);
                cB0 = __builtin_elementwise_fma(KB1[2], f2{B1.x, B1.y}, cB0);
                cB1 = __builtin_elementwise_fma(KB1[3], f2{B1.z, B1.w}, cB1);
                cA0 = __builtin_elementwise_fma(KA1[4], f2{B2.x, B2.y}, cA0);
                cA1 = __builtin_elementwise_fma(KA1[5], f2{B2.z, B2.w}, cA1);
                cB0 = __builtin_elementwise_fma(KB1[4], f2{B2.x, B2.y}, cB0);
                cB1 = __builtin_elementwise_fma(KB1[5], f2{B2.z, B2.w}, cB1);
                cA0 = __builtin_elementwise_fma(KA1[6], f2{B3.x, B3.y}, cA0);
                cA1 = __builtin_elementwise_fma(KA1[7], f2{B3.z, B3.w}, cA1);
                cB0 = __builtin_elementwise_fma(KB1[6], f2{B3.x, B3.y}, cB0);
                cB1 = __builtin_elementwise_fma(KB1[7], f2{B3.z, B3.w}, cB1);
                f2 aa1 = cA0 + cA1;
                f2 bb1 = cB0 + cB1;
                float pa1 = aa1.x + aa1.y;
                float pb1 = bb1.x + bb1.y;
                // combine + update, both chains
                float o0 = __shfl_xor(pb0, 16);
                float o1 = __shfl_xor(pb1, 16);
                w0p = w0c;
                w0c = __builtin_amdgcn_rcpf(pa0 + o0) * E0;
                w1p = w1c;
                w1c = __builtin_amdgcn_rcpf(pa1 + o1) * E1;
                swv0[h * 32 + i] = w0c;
                swv1[h * 32 + i] = w1c;
            }
            if (blk < 8) {
                float d0 = __builtin_amdgcn_logf(w0c);
                float d1 = __builtin_amdgcn_logf(w1c);
                pp0 += d0;
                pp1 += d1;
                spv0[h * 32 + i] = d0;
                spv1[h * 32 + i] = d1;
                {
                    const float4* dv = (const float4*)(&spv0[h * 32 + q * 16]);
                    float4 D0 = dv[0], D1 = dv[1], D2 = dv[2], D3 = dv[3];
                    float ex[16];
                    ex[0]  = __builtin_amdgcn_exp2f(D0.x);
                    ex[1]  = __builtin_amdgcn_exp2f(D0.y);
                    ex[2]  = __builtin_amdgcn_exp2f(D0.z);
                    ex[3]  = __builtin_amdgcn_exp2f(D0.w);
                    ex[4]  = __builtin_amdgcn_exp2f(D1.x);
                    ex[5]  = __builtin_amdgcn_exp2f(D1.y);
                    ex[6]  = __builtin_amdgcn_exp2f(D1.z);
                    ex[7]  = __builtin_amdgcn_exp2f(D1.w);
                    ex[8]  = __builtin_amdgcn_exp2f(D2.x);
                    ex[9]  = __builtin_amdgcn_exp2f(D2.y);
                    ex[10] = __builtin_amdgcn_exp2f(D2.z);
                    ex[11] = __builtin_amdgcn_exp2f(D2.w);
                    ex[12] = __builtin_amdgcn_exp2f(D3.x);
                    ex[13] = __builtin_amdgcn_exp2f(D3.y);
                    ex[14] = __builtin_amdgcn_exp2f(D3.z);
                    ex[15] = __builtin_amdgcn_exp2f(D3.w);
                    #pragma unroll
                    for (int t2 = 0; t2 < 8; ++t2) {
                        f2 ee = f2{ex[2 * t2], ex[2 * t2 + 1]};
                        KA0[t2] *= ee;
                        KB0[t2] *= ee;
                    }
                }
                {
                    const float4* dv = (const float4*)(&spv1[h * 32 + q * 16]);
                    float4 D0 = dv[0], D1 = dv[1], D2 = dv[2], D3 = dv[3];
                    float ex[16];
                    ex[0]  = __builtin_amdgcn_exp2f(D0.x);
                    ex[1]  = __builtin_amdgcn_exp2f(D0.y);
                    ex[2]  = __builtin_amdgcn_exp2f(D0.z);
                    ex[3]  = __builtin_amdgcn_exp2f(D0.w);
                    ex[4]  = __builtin_amdgcn_exp2f(D1.x);
                    ex[5]  = __builtin_amdgcn_exp2f(D1.y);
                    ex[6]  = __builtin_amdgcn_exp2f(D1.z);
                    ex[7]  = __builtin_amdgcn_exp2f(D1.w);
                    ex[8]  = __builtin_amdgcn_exp2f(D2.x);
                    ex[9]  = __builtin_amdgcn_exp2f(D2.y);
                    ex[10] = __builtin_amdgcn_exp2f(D2.z);
                    ex[11] = __builtin_amdgcn_exp2f(D2.w);
                    ex[12] = __builtin_amdgcn_exp2f(D3.x);
                    ex[13] = __builtin_amdgcn_exp2f(D3.y);
                    ex[14] = __builtin_amdgcn_exp2f(D3.z);
                    ex[15] = __builtin_amdgcn_exp2f(D3.w);
                    #pragma unroll
                    for (int t2 = 0; t2 < 8; ++t2) {
                        f2 ee = f2{ex[2 * t2], ex[2 * t2 + 1]};
                        KA1[t2] *= ee;
                        KB1[t2] *= ee;
                    }
                }
                E0 = __builtin_amdgcn_exp2f(-pp0);
                E1 = __builtin_amdgcn_exp2f(-pp1);
                w0c = 1.0f;
                w1c = 1.0f;
                swv0[lane] = 1.0f;
                swv1[lane] = 1.0f;
            }
        }

        // z99 = pp + log2(wprev), z100 = pp + log2(wcur); cost = eps*ln2*sum/32
        float zs0 = 2.0f * pp0 + __builtin_amdgcn_logf(w0p)
                  + __builtin_amdgcn_logf(w0c);
        float zs1 = 2.0f * pp1 + __builtin_amdgcn_logf(w1p)
                  + __builtin_amdgcn_logf(w1c);
        #pragma unroll
        for (int off = 16; off > 0; off >>= 1) {
            zs0 += __shfl_xor(zs0, off);
            zs1 += __shfl_xor(zs1, off);
        }
        if (i == 0) {
            unsafeAtomicAdd(&dist[P0],     -0.5f * (zs0 * (EPS_F * LN2_F / 32.0f)));
            unsafeAtomicAdd(&dist[P0 + 1], -0.5f * (zs1 * (EPS_F * LN2_F / 32.0f)));
        }
    } else {
        // ============ off-diagonal path: half-wave per pair ============
        int h = lane >> 5, l = lane & 31;
        int p = (blockIdx.x - 2048) * 4 + w * 2 + h;   // 2048*4 = 8192 pairs

        float* base = S + h * 640;
        float* sX = base;
        float* sY = base + 256;
        float* sf = base + 512;
        float* sg = base + 544;
        float* su = base + 576;
        float* sv = base + 608;

        {
            const float4* zx = (const float4*)(Z + (size_t)p * 256);
            const float4* zy = (const float4*)(Z + (size_t)(N_PAIRS + p) * 256);
            *(float4*)(&sX[l * 8])     = zx[l * 2];
            *(float4*)(&sX[l * 8 + 4]) = zx[l * 2 + 1];
            *(float4*)(&sY[l * 8])     = zy[l * 2];
            *(float4*)(&sY[l * 8 + 4]) = zy[l * 2 + 1];
        }
        sg[l] = 0.0f;

        // Crow[j] = C2[l][j]; Ccol[i] = C2[i][l]
        f2 Crow[16], Ccol[16];
        {
            const f2* xp = (const f2*)(&sX[l * 8]);
            f2 x0 = xp[0], x1 = xp[1], x2 = xp[2], x3 = xp[3];
            const f2* yp = (const f2*)(&sY[l * 8]);
            f2 y0 = yp[0], y1 = yp[1], y2 = yp[2], y3 = yp[3];
            #pragma unroll
            for (int t = 0; t < 32; ++t) {
                const f2* op = (const f2*)(&sY[t * 8]);
                f2 d, s2;
                d = x0 - op[0]; s2 = d * d;
                d = x1 - op[1]; s2 = __builtin_elementwise_fma(d, d, s2);
                d = x2 - op[2]; s2 = __builtin_elementwise_fma(d, d, s2);
                d = x3 - op[3]; s2 = __builtin_elementwise_fma(d, d, s2);
                float d2 = s2.x + s2.y + 1e-12f;
                Crow[t >> 1][t & 1] = fmaf(__builtin_amdgcn_sqrtf(d2), CSCALE, CBIAS);
                const f2* qp = (const f2*)(&sX[t * 8]);
                d = qp[0] - y0; s2 = d * d;
                d = qp[1] - y1; s2 = __builtin_elementwise_fma(d, d, s2);
                d = qp[2] - y2; s2 = __builtin_elementwise_fma(d, d, s2);
                d = qp[3] - y3; s2 = __builtin_elementwise_fma(d, d, s2);
                float e2 = s2.x + s2.y + 1e-12f;
                Ccol[t >> 1][t & 1] = fmaf(__builtin_amdgcn_sqrtf(e2), CSCALE, CBIAS);
            }
        }

        float ft = 0.0f, gt = 0.0f;

        // Phase A: 2 log-domain iterations (full 32-wide LSE per lane, no shfl)
        #pragma unroll 1
        for (int it = 0; it < 2; ++it) {
            {
                const float4* gp = (const float4*)sg;
                float4 G[8];
                #pragma unroll
                for (int r = 0; r < 8; ++r) G[r] = gp[r];
                f2 val[16], m2 = f2{-1e30f, -1e30f};
                #pragma unroll
                for (int r = 0; r < 8; ++r) {
                    val[2 * r]     = f2{G[r].x, G[r].y} + Crow[2 * r];
                    val[2 * r + 1] = f2{G[r].z, G[r].w} + Crow[2 * r + 1];
                    m2 = __builtin_elementwise_max(m2, val[2 * r]);
                    m2 = __builtin_elementwise_max(m2, val[2 * r + 1]);
                }
                float m = fmaxf(m2.x, m2.y);
                f2 mm = f2{m, m};
                float s0 = 0.0f, s1 = 0.0f;
                #pragma unroll
                for (int t2 = 0; t2 < 16; ++t2) {
                    f2 e = val[t2] - mm;
                    s0 += __builtin_amdgcn_exp2f(e.x);
                    s1 += __builtin_amdgcn_exp2f(e.y);
                }
                ft = -(m + __builtin_amdgcn_logf(s0 + s1));
            }
            sf[l] = ft;
            {
                const float4* fp = (const float4*)sf;
                float4 F[8];
                #pragma unroll
                for (int r = 0; r < 8; ++r) F[r] = fp[r];
                f2 val[16], m2 = f2{-1e30f, -1e30f};
                #pragma unroll
                for (int r = 0; r < 8; ++r) {
                    val[2 * r]     = f2{F[r].x, F[r].y} + Ccol[2 * r];
                    val[2 * r + 1] = f2{F[r].z, F[r].w} + Ccol[2 * r + 1];
                    m2 = __builtin_elementwise_max(m2, val[2 * r]);
                    m2 = __builtin_elementwise_max(m2, val[2 * r + 1]);
                }
                float m = fmaxf(m2.x, m2.y);
                f2 mm = f2{m, m};
                float s0 = 0.0f, s1 = 0.0f;
                #pragma unroll
                for (int t2 = 0; t2 < 16; ++t2) {
                    f2 e = val[t2] - mm;
                    s0 += __builtin_amdgcn_exp2f(e.x);
                    s1 += __builtin_amdgcn_exp2f(e.y);
                }
                gt = -(m + __builtin_amdgcn_logf(s0 + s1));
            }
            sg[l] = gt;
        }

        // Build K (row copy + col copy); C dies here.
        f2 KR[16], KC[16];
        {
            const float4* gp = (const float4*)sg;
            #pragma unroll
            for (int r = 0; r < 8; ++r) {
                float4 G = gp[r];
                f2 a0 = f2{G.x, G.y} + Crow[2 * r] + f2{ft, ft};
                f2 a1 = f2{G.z, G.w} + Crow[2 * r + 1] + f2{ft, ft};
                KR[2 * r].x     = __builtin_amdgcn_exp2f(a0.x);
                KR[2 * r].y     = __builtin_amdgcn_exp2f(a0.y);
                KR[2 * r + 1].x = __builtin_amdgcn_exp2f(a1.x);
                KR[2 * r + 1].y = __builtin_amdgcn_exp2f(a1.y);
            }
            const float4* fp = (const float4*)sf;
            #pragma unroll
            for (int r = 0; r < 8; ++r) {
                float4 F = fp[r];
                f2 a0 = f2{F.x, F.y} + Ccol[2 * r] + f2{gt, gt};
                f2 a1 = f2{F.z, F.w} + Ccol[2 * r + 1] + f2{gt, gt};
                KC[2 * r].x     = __builtin_amdgcn_exp2f(a0.x);
                KC[2 * r].y     = __builtin_amdgcn_exp2f(a0.y);
                KC[2 * r + 1].x = __builtin_amdgcn_exp2f(a1.x);
                KC[2 * r + 1].y = __builtin_amdgcn_exp2f(a1.y);
            }
        }
        sv[l] = 1.0f;
        float ureg = 1.0f, vreg = 1.0f;

        const int blens[5] = {6, 6, 12, 12, 12};   // 48 exp iters total
        #pragma unroll 1
        for (int blk = 0; blk < 5; ++blk) {
            int L = blens[blk];
            #pragma unroll 2
            for (int s6 = 0; s6 < L; ++s6) {
                // f-step: u_l = 1/(KR . v), full dot, no shfl
                {
                    const float4* vp = (const float4*)sv;
                    f2 acc0, acc1;
                    float4 A = vp[0];
                    acc0 = KR[0] * f2{A.x, A.y};
                    acc1 = KR[1] * f2{A.z, A.w};
                    #pragma unroll
                    for (int r = 1; r < 8; ++r) {
                        float4 B = vp[r];
                        acc0 = __builtin_elementwise_fma(KR[2 * r],     f2{B.x, B.y}, acc0);
                        acc1 = __builtin_elementwise_fma(KR[2 * r + 1], f2{B.z, B.w}, acc1);
                    }
                    f2 a = acc0 + acc1;
                    ureg = __builtin_amdgcn_rcpf(a.x + a.y);
                }
                su[l] = ureg;
                // g-step: v_l = 1/(KC . u)
                {
                    const float4* up = (const float4*)su;
                    f2 acc0, acc1;
                    float4 A = up[0];
                    acc0 = KC[0] * f2{A.x, A.y};
                    acc1 = KC[1] * f2{A.z, A.w};
                    #pragma unroll
                    for (int r = 1; r < 8; ++r) {
                        float4 B = up[r];
                        acc0 = __builtin_elementwise_fma(KC[2 * r],     f2{B.x, B.y}, acc0);
                        acc1 = __builtin_elementwise_fma(KC[2 * r + 1], f2{B.z, B.w}, acc1);
                    }
                    f2 a = acc0 + acc1;
                    vreg = __builtin_amdgcn_rcpf(a.x + a.y);
                }
                sv[l] = vreg;
            }
            if (blk < 4) {
                float df = __builtin_amdgcn_logf(ureg);
                float dg = __builtin_amdgcn_logf(vreg);
                ft += df;
                gt += dg;
                sf[l] = df;
                sg[l] = dg;
                // KR[j] *= exp2(df + dg_j); KC[i] *= exp2(dg + df_i)
                const float4* dgv = (const float4*)sg;
                #pragma unroll
                for (int r = 0; r < 8; ++r) {
                    float4 D = dgv[r];
                    f2 e0, e1;
                    e0.x = __builtin_amdgcn_exp2f(df + D.x);
                    e0.y = __builtin_amdgcn_exp2f(df + D.y);
                    e1.x = __builtin_amdgcn_exp2f(df + D.z);
                    e1.y = __builtin_amdgcn_exp2f(df + D.w);
                    KR[2 * r]     *= e0;
                    KR[2 * r + 1] *= e1;
                }
                const float4* dfv = (const float4*)sf;
                #pragma unroll
                for (int r = 0; r < 8; ++r) {
                    float4 D = dfv[r];
                    f2 e0, e1;
                    e0.x = __builtin_amdgcn_exp2f(dg + D.x);
                    e0.y = __builtin_amdgcn_exp2f(dg + D.y);
                    e1.x = __builtin_amdgcn_exp2f(dg + D.z);
                    e1.y = __builtin_amdgcn_exp2f(dg + D.w);
                    KC[2 * r]     *= e0;
                    KC[2 * r + 1] *= e1;
                }
                sv[l] = 1.0f;
                ureg = 1.0f;
                vreg = 1.0f;
            }
        }
        ft += __builtin_amdgcn_logf(ureg);
        gt += __builtin_amdgcn_logf(vreg);

        // OT = eps*ln2*(sum_l f_l + g_l)/32; reduce within half-wave
        float v = ft + gt;
        #pragma unroll
        for (int off = 16; off > 0; off >>= 1) v += __shfl_xor(v, off);
        if (l == 0) {
            float cost = v * (EPS_F * LN2_F / 32.0f);
            unsafeAtomicAdd(&dist[p], cost);
        }
    }
}

// ------------------------------------------------------------------ finalize
__global__ __launch_bounds__(1024) void k_finalize(
        const float* __restrict__ dist,
        const float* __restrict__ gd, float* __restrict__ out) {
    __shared__ float red[1024];
    float s = 0.0f;
    for (int i = threadIdx.x; i < N_PAIRS; i += 1024) {
        float g = gd[i];
        s += fabsf(dist[i] - g) / g;
    }
    red[threadIdx.x] = s;
    __syncthreads();
    for (int o = 512; o > 0; o >>= 1) {
        if (threadIdx.x < o) red[threadIdx.x] += red[threadIdx.x + o];
        __syncthreads();
    }
    if (threadIdx.x == 0) out[0] = red[0] * (1.0f / N_PAIRS);
}

// -------------------------------------------------------------------- launch
extern "C" void kernel_launch(void* const* d_in, const int* in_sizes, int n_in,
                              void* d_out, int out_size, void* d_ws, size_t ws_size,
                              hipStream_t stream) {
    const float* x    = (const float*)d_in[0];   // [50000,128]
    const float* W    = (const float*)d_in[1];   // [128,256]
    const int*   eidx = (const int*)d_in[2];     // [2,800000]
    const int*   pair = (const int*)d_in[3];     // [2,8192] flat = 16384 slots
    const float* gd   = (const float*)d_in[4];   // [8192]

    char* ws = (char*)d_ws;
    size_t off = 0;
    int*   cnt    = (int*)  (ws + off); off += (size_t)N_NODES * 4;
    int*   flags  = (int*)  (ws + off); off += (size_t)N_NODES * 4;
    float* dist   = (float*)(ws + off); off += (size_t)N_PAIRS * 4;
    size_t zero_bytes = off;                     // cnt+flags+dist contiguous
    int*   bucket = (int*)  (ws + off); off += (size_t)N_NODES * CAP * 4; // 12.8 MB
    float* Z      = (float*)(ws + off); off += (size_t)N_SLOTS * 256 * 4; // 16.8 MB

    hipMemsetAsync(d_ws, 0, zero_bytes, stream);
    k_mark    <<<(N_SLOTS + 255) / 256, 256, 0, stream>>>(pair, flags);
    k_scatter <<<N_EDGES / 256, 256, 0, stream>>>(eidx, flags, cnt, bucket);
    k_gemm    <<<N_SLOTS / 16, 256, 0, stream>>>(pair, x, cnt, bucket, W, Z);
    k_sinkhorn<<<4096, 128, 0, stream>>>(Z, dist);
    k_finalize<<<1, 1024, 0, stream>>>(dist, gd, (float*)d_out);
}